// Round 11
// baseline (2288.185 us; speedup 1.0000x reference)
//
#include <hip/hip_runtime.h>
#include <hip/hip_bf16.h>
#include <hip/hip_fp16.h>

// RepWalk on MI355X (gfx950). Inputs fp32, output fp32 (verified r4).
// Round 11: LSTM is per-CU L2-stream bound (96 GB/s/CU on 720KB/step fp16 Whh).
// With 1 block/CU we own the CU: cache 40% of Whh on-CU per dispatch —
// 12 rows/group in VGPRs (uint4 warr[12], ~48 regs) + 8 rows/group in LDS
// (115KB) — loaded once, reused 32 steps. Streamed portion: 432KB/step.
// Everything else unchanged from r10.

typedef unsigned short u16;
typedef __attribute__((ext_vector_type(8))) short short8;
typedef __attribute__((ext_vector_type(4))) float floatx4;

#define NEGV -1e9f
#define MFMA __builtin_amdgcn_mfma_f32_16x16x32_bf16

__device__ __forceinline__ float bf2f(u16 u) {
    union { unsigned int i; float f; } x; x.i = ((unsigned int)u) << 16; return x.f;
}
__device__ __forceinline__ u16 f2bf(float f) {
    unsigned int u = __float_as_uint(f);
    unsigned int r = (u + 0x7fff + ((u >> 16) & 1)) >> 16;
    return (u16)r;
}
__device__ __forceinline__ float sigm(float x) { return 1.f / (1.f + expf(-x)); }
__device__ __forceinline__ float rdf(const void* p, size_t i, int flag) {
    return flag ? ((const float*)p)[i] : bf2f(((const u16*)p)[i]);
}

// ---------------- dtype detect ----------------
__global__ void k_detect(const void* __restrict__ emb, int* __restrict__ flag) {
    __shared__ int cnt;
    if (threadIdx.x == 0) cnt = 0;
    __syncthreads();
    u16 x = ((const u16*)emb)[4096 + threadIdx.x];
    int e = (x >> 7) & 0xFF;
    if (e >= 0x8A) atomicAdd(&cnt, 1);
    __syncthreads();
    if (threadIdx.x == 0) *flag = (cnt > 8) ? 1 : 0;
}

// ---------------- small prep ----------------
__global__ void k_prep_small(const int* __restrict__ text, const int* __restrict__ asp,
                             int* __restrict__ lens) {
    int tid = threadIdx.x;
    if (tid < 64) {
        int c = 0;
        for (int s = 0; s < 128; ++s) c += (text[tid * 128 + s] != 0);
        lens[tid] = c;
    } else if (tid < 128) {
        int b = tid - 64; int c = 0;
        for (int a = 0; a < 8; ++a) c += (asp[b * 8 + a] != 0);
        lens[64 + b] = c;
    }
}

// both Wih layers -> padded [2432,320] hi/lo each
__global__ void k_pad_wih2(const void* __restrict__ W1, const void* __restrict__ W2,
                           const int* __restrict__ flag,
                           u16* __restrict__ d1h, u16* __restrict__ d1l,
                           u16* __restrict__ d2h, u16* __restrict__ d2l) {
    int i = blockIdx.x * 256 + threadIdx.x;
    if (i >= 2 * 2432 * 320) return;
    int f = *flag;
    int layer = i / (2432 * 320), r = i - layer * (2432 * 320);
    int n = r / 320, k = r - n * 320;
    const void* W = layer ? W2 : W1;
    float val = (n < 2400 && k < 300) ? rdf(W, (size_t)n * 300 + k, f) : 0.f;
    u16 hi = f2bf(val);
    float lo = val - bf2f(hi);
    if (layer) { d2h[r] = hi; d2l[r] = f2bf(lo); }
    else       { d1h[r] = hi; d1l[r] = f2bf(lo); }
}

// both Whh layers -> WhhT fp16 [2,300,1200] each
__global__ void k_whhT2(const void* __restrict__ W1, const void* __restrict__ W2,
                        const int* __restrict__ flag,
                        u16* __restrict__ d1, u16* __restrict__ d2) {
    int i = blockIdx.x * 256 + threadIdx.x;
    if (i >= 2 * 720000) return;
    int f = *flag;
    int layer = i / 720000, r = i - layer * 720000;
    int dir = r / 360000, rr = r - dir * 360000;
    int k = rr / 1200, g = rr - k * 1200;
    const void* W = layer ? W2 : W1;
    float val = rdf(W, (size_t)dir * 360000 + (size_t)g * 300 + k, f);
    __half hh = __float2half(val);
    u16 bits = *reinterpret_cast<u16*>(&hh);
    if (layer) d2[r] = bits; else d1[r] = bits;
}

// lin1_W [2,600,1200] -> padded [2,640,1216] hi/lo
__global__ void k_pad_lin1(const void* __restrict__ W, const int* __restrict__ flag,
                           u16* __restrict__ dhi, u16* __restrict__ dlo) {
    int i = blockIdx.x * 256 + threadIdx.x;
    if (i >= 2 * 640 * 1216) return;
    int f = *flag;
    int dir = i / (640 * 1216), r = i - dir * (640 * 1216);
    int n = r / 1216, k = r - n * 1216;
    float val = (n < 600 && k < 1200)
        ? rdf(W, (size_t)dir * 720000 + (size_t)n * 1200 + k, f) : 0.f;
    u16 hi = f2bf(val);
    dhi[i] = hi;
    dlo[i] = f2bf(val - bf2f(hi));
}

// smallf = pw(8192)|l2w(1200)|l2b(2)|fcw(1800)|fcb(3); bl[1280]; bias_t/a[2400]
__global__ void k_small(const void* pw, const void* l2w, const void* l2b,
                        const void* fcw, const void* fcb, const void* lb,
                        const void* b1i, const void* b1h, const void* b2i, const void* b2h,
                        const int* __restrict__ flag,
                        float* __restrict__ dst, float* __restrict__ bl,
                        float* __restrict__ bt, float* __restrict__ ba) {
    int i = blockIdx.x * 256 + threadIdx.x;
    int f = *flag;
    if (i < 8192)            dst[i] = rdf(pw, i, f);
    else if (i < 9392)       dst[i] = rdf(l2w, i - 8192, f);
    else if (i < 9394)       dst[i] = rdf(l2b, i - 9392, f);
    else if (i < 11194)      dst[i] = rdf(fcw, i - 9394, f);
    else if (i < 11197)      dst[i] = rdf(fcb, i - 11194, f);
    if (i < 1280) {
        int dir = i / 640, c = i - dir * 640;
        bl[i] = (c < 600) ? rdf(lb, dir * 600 + c, f) : 0.f;
    }
    if (i < 2400) {
        bt[i] = rdf(b1i, i, f) + rdf(b1h, i, f);
        ba[i] = rdf(b2i, i, f) + rdf(b2h, i, f);
    }
}

// ---------------- fused gather xproj GEMM ----------------
__global__ __launch_bounds__(256) void gemm_emb(
    const void* __restrict__ emb, const int* __restrict__ ids,
    int base, int rpb, int stride, const int* __restrict__ flag,
    const u16* __restrict__ Bhi, const u16* __restrict__ Blo,
    const float* __restrict__ bias,
    float* __restrict__ C, int ldc, int nstore)
{
    int f = *flag;
    int tid = threadIdx.x;
    int wave = tid >> 6, lane = tid & 63;
    int l15 = lane & 15, quad = lane >> 4;
    int m0 = blockIdx.x * 64 + wave * 16;
    int n0 = blockIdx.y * 64;

    int m = m0 + l15;
    int b = m / rpb, j = m - b * rpb;
    int id = ids[b * stride + base + j];
    const float* arow_f = (const float*)emb + (size_t)id * 300;
    const u16*   arow_b = (const u16*)emb + (size_t)id * 300;

    const u16* Bp  = Bhi + (size_t)(n0 + l15) * 320 + quad * 8;
    const u16* Bp2 = Blo + (size_t)(n0 + l15) * 320 + quad * 8;

    floatx4 acc0 = {0.f, 0.f, 0.f, 0.f};
    floatx4 acc1 = acc0, acc2 = acc0, acc3 = acc0;

    for (int kc = 0; kc < 10; ++kc) {
        int ko = kc * 32 + quad * 8;
        short8 ahi, alo;
        if (f) {
            if (ko + 8 <= 300) {
                float4 fa = *(const float4*)(arow_f + ko);
                float4 fb = *(const float4*)(arow_f + ko + 4);
                float vv[8] = {fa.x, fa.y, fa.z, fa.w, fb.x, fb.y, fb.z, fb.w};
                #pragma unroll
                for (int t = 0; t < 8; ++t) {
                    u16 h = f2bf(vv[t]);
                    ahi[t] = (short)h;
                    alo[t] = (short)f2bf(vv[t] - bf2f(h));
                }
            } else {
                #pragma unroll
                for (int t = 0; t < 8; ++t) {
                    int k = ko + t;
                    float vv = (k < 300) ? arow_f[k] : 0.f;
                    u16 h = f2bf(vv);
                    ahi[t] = (short)h;
                    alo[t] = (short)f2bf(vv - bf2f(h));
                }
            }
        } else {
            #pragma unroll
            for (int t = 0; t < 8; ++t) {
                int k = ko + t;
                ahi[t] = (k < 300) ? (short)arow_b[k] : (short)0;
                alo[t] = 0;
            }
        }
        int ko2 = kc * 32;
        short8 bh0 = *(const short8*)(Bp + ko2);
        short8 bh1 = *(const short8*)(Bp + (size_t)16 * 320 + ko2);
        short8 bh2 = *(const short8*)(Bp + (size_t)32 * 320 + ko2);
        short8 bh3 = *(const short8*)(Bp + (size_t)48 * 320 + ko2);
        short8 bl0 = *(const short8*)(Bp2 + ko2);
        short8 bl1 = *(const short8*)(Bp2 + (size_t)16 * 320 + ko2);
        short8 bl2 = *(const short8*)(Bp2 + (size_t)32 * 320 + ko2);
        short8 bl3 = *(const short8*)(Bp2 + (size_t)48 * 320 + ko2);
        acc0 = MFMA(ahi, bh0, acc0, 0, 0, 0);
        acc1 = MFMA(ahi, bh1, acc1, 0, 0, 0);
        acc2 = MFMA(ahi, bh2, acc2, 0, 0, 0);
        acc3 = MFMA(ahi, bh3, acc3, 0, 0, 0);
        acc0 = MFMA(ahi, bl0, acc0, 0, 0, 0);
        acc1 = MFMA(ahi, bl1, acc1, 0, 0, 0);
        acc2 = MFMA(ahi, bl2, acc2, 0, 0, 0);
        acc3 = MFMA(ahi, bl3, acc3, 0, 0, 0);
        acc0 = MFMA(alo, bh0, acc0, 0, 0, 0);
        acc1 = MFMA(alo, bh1, acc1, 0, 0, 0);
        acc2 = MFMA(alo, bh2, acc2, 0, 0, 0);
        acc3 = MFMA(alo, bh3, acc3, 0, 0, 0);
    }

    #pragma unroll
    for (int c = 0; c < 4; ++c) {
        floatx4 acc = (c == 0) ? acc0 : (c == 1) ? acc1 : (c == 2) ? acc2 : acc3;
        int col = n0 + c * 16 + l15;
        if (col >= nstore) continue;
        float bb = bias[col];
        #pragma unroll
        for (int r = 0; r < 4; ++r) {
            int row = m0 + quad * 4 + r;
            C[(size_t)row * ldc + col] = acc[r] + bb;
        }
    }
}

// ---------------- MFMA GEMM (lin1): fused epilogue ----------------
__global__ __launch_bounds__(256) void gemm_bt(
    const u16* __restrict__ Ahi, const u16* __restrict__ Alo, int lda,
    const u16* __restrict__ Bhi, const u16* __restrict__ Blo, int ldb,
    const float* __restrict__ bias,
    int nstore, int K,
    const float* __restrict__ tg, const float* __restrict__ pw, float* __restrict__ vio,
    int mrowoff)
{
    int tid = threadIdx.x;
    int wave = tid >> 6, lane = tid & 63;
    int l15 = lane & 15, quad = lane >> 4;
    int m0 = blockIdx.x * 64 + wave * 16;
    int n0 = blockIdx.y * 64;

    const u16* Ap  = Ahi + (size_t)(m0 + l15) * lda + quad * 8;
    const u16* Ap2 = Alo + (size_t)(m0 + l15) * lda + quad * 8;
    const u16* Bp  = Bhi + (size_t)(n0 + l15) * ldb + quad * 8;
    const u16* Bp2 = Blo + (size_t)(n0 + l15) * ldb + quad * 8;

    floatx4 acc0 = {0.f, 0.f, 0.f, 0.f};
    floatx4 acc1 = acc0, acc2 = acc0, acc3 = acc0;

    int nk = K >> 5;
    for (int kc = 0; kc < nk; ++kc) {
        int ko = kc * 32;
        short8 bh0 = *(const short8*)(Bp + ko);
        short8 bh1 = *(const short8*)(Bp + (size_t)16 * ldb + ko);
        short8 bh2 = *(const short8*)(Bp + (size_t)32 * ldb + ko);
        short8 bh3 = *(const short8*)(Bp + (size_t)48 * ldb + ko);
        short8 bl0 = *(const short8*)(Bp2 + ko);
        short8 bl1 = *(const short8*)(Bp2 + (size_t)16 * ldb + ko);
        short8 bl2 = *(const short8*)(Bp2 + (size_t)32 * ldb + ko);
        short8 bl3 = *(const short8*)(Bp2 + (size_t)48 * ldb + ko);
        short8 a  = *(const short8*)(Ap + ko);
        short8 al = *(const short8*)(Ap2 + ko);
        acc0 = MFMA(a, bh0, acc0, 0, 0, 0);
        acc1 = MFMA(a, bh1, acc1, 0, 0, 0);
        acc2 = MFMA(a, bh2, acc2, 0, 0, 0);
        acc3 = MFMA(a, bh3, acc3, 0, 0, 0);
        acc0 = MFMA(a, bl0, acc0, 0, 0, 0);
        acc1 = MFMA(a, bl1, acc1, 0, 0, 0);
        acc2 = MFMA(a, bl2, acc2, 0, 0, 0);
        acc3 = MFMA(a, bl3, acc3, 0, 0, 0);
        acc0 = MFMA(al, bh0, acc0, 0, 0, 0);
        acc1 = MFMA(al, bh1, acc1, 0, 0, 0);
        acc2 = MFMA(al, bh2, acc2, 0, 0, 0);
        acc3 = MFMA(al, bh3, acc3, 0, 0, 0);
    }

    #pragma unroll
    for (int c = 0; c < 4; ++c) {
        floatx4 acc = (c == 0) ? acc0 : (c == 1) ? acc1 : (c == 2) ? acc2 : acc3;
        int col = n0 + c * 16 + l15;
        if (col >= nstore) continue;
        float bb = bias[col];
        #pragma unroll
        for (int r = 0; r < 4; ++r) {
            int row = m0 + quad * 4 + r;
            float val = acc[r] + bb;
            val = val > 0.f ? val : 0.01f * val;      // leaky_relu
            int rg = row + mrowoff;
            float t = tg[rg];
            size_t vi = (size_t)rg * 600 + col;
            float vv = vio[vi];
            vio[vi] = pw[rg] * ((1.f - t) * val + t * vv);
        }
    }
}

// ---------------- LSTM recurrence: on-CU weight cache (VGPR 12 + LDS 8 rows/group) ----
// 960 threads = 6 k-groups x 160 (150 active). Group g covers k in [50g,50g+50).
// Thread u: gate-cols 8u..8u+7. Rows 0-11: VGPR warr; rows 12-19: LDS wlds;
// rows 20-49: streamed from L2. Blocks >= 128 run the fused aspect path.
__global__ __launch_bounds__(960, 1) void k_lstm5(
    const float* __restrict__ xf, const float* __restrict__ xb, int ldx, int rpb,
    int base_f, int base_b, const u16* __restrict__ whhT,
    const int* __restrict__ lens, float* __restrict__ out, int T, int init,
    float* __restrict__ hst, float* __restrict__ cst, int nsteps,
    const float* __restrict__ xa, const u16* __restrict__ whhA,
    const int* __restrict__ lensA, float* __restrict__ outA,
    float* __restrict__ hstA, float* __restrict__ cstA)
{
    __shared__ float h_s[300];
    __shared__ float part[6][1200];
    __shared__ u16 wlds[6][8][1200];
    int blk = blockIdx.x;
    if (blk >= 128) {                     // fused aspect chain
        blk -= 128;
        xf = xa; xb = xa + 1200; ldx = 2400; rpb = 8;
        base_f = 0; base_b = 0;
        whhT = whhA; lens = lensA; out = outA; T = 8; init = 1;
        hst = hstA; cst = cstA; nsteps = 8;
    }
    int tid = threadIdx.x;
    int g6 = tid / 160, u = tid - g6 * 160;
    bool act = (u < 150);
    int b = blk >> 1, dir = blk & 1;
    int len = lens[b];
    float c = 0.f;
    const u16* wbase = whhT + (size_t)dir * 360000 + (size_t)g6 * 50 * 1200 + 8 * u;

    // preload weight cache: rows 0-11 -> VGPRs, rows 12-19 -> LDS
    uint4 warr[12];
    if (act) {
        #pragma unroll
        for (int i = 0; i < 12; ++i)
            warr[i] = *(const uint4*)(wbase + (size_t)i * 1200);
        #pragma unroll
        for (int r = 0; r < 8; ++r)
            *(uint4*)&wlds[g6][r][8 * u] = *(const uint4*)(wbase + (size_t)(12 + r) * 1200);
    }
    if (tid < 300) {
        h_s[tid] = init ? 0.f : hst[(size_t)blk * 300 + tid];
        c = init ? 0.f : cst[(size_t)blk * 300 + tid];
    }
    __syncthreads();
    const u16* wstream = wbase + (size_t)20 * 1200;

    for (int s = 0; s < nsteps; ++s) {
        int pos = dir ? (base_b + nsteps - 1 - s) : (base_f + s);
        if (pos >= len) continue;           // block-uniform skip
        if (act) {
            float a0 = 0.f, a1 = 0.f, a2 = 0.f, a3 = 0.f;
            float a4 = 0.f, a5 = 0.f, a6 = 0.f, a7 = 0.f;
            const float* hs = h_s + g6 * 50;
            // phase 1: VGPR-cached rows 0-11
            #pragma unroll
            for (int i = 0; i < 12; ++i) {
                float hk = hs[i];
                uint4 wv = warr[i];
                float2 f0 = __half22float2(*(__half2*)&wv.x);
                float2 f1 = __half22float2(*(__half2*)&wv.y);
                float2 f2 = __half22float2(*(__half2*)&wv.z);
                float2 f3 = __half22float2(*(__half2*)&wv.w);
                a0 = fmaf(hk, f0.x, a0); a1 = fmaf(hk, f0.y, a1);
                a2 = fmaf(hk, f1.x, a2); a3 = fmaf(hk, f1.y, a3);
                a4 = fmaf(hk, f2.x, a4); a5 = fmaf(hk, f2.y, a5);
                a6 = fmaf(hk, f3.x, a6); a7 = fmaf(hk, f3.y, a7);
            }
            // phase 2: LDS-cached rows 12-19
            #pragma unroll
            for (int i = 0; i < 8; ++i) {
                float hk = hs[12 + i];
                uint4 wv = *(const uint4*)&wlds[g6][i][8 * u];
                float2 f0 = __half22float2(*(__half2*)&wv.x);
                float2 f1 = __half22float2(*(__half2*)&wv.y);
                float2 f2 = __half22float2(*(__half2*)&wv.z);
                float2 f3 = __half22float2(*(__half2*)&wv.w);
                a0 = fmaf(hk, f0.x, a0); a1 = fmaf(hk, f0.y, a1);
                a2 = fmaf(hk, f1.x, a2); a3 = fmaf(hk, f1.y, a3);
                a4 = fmaf(hk, f2.x, a4); a5 = fmaf(hk, f2.y, a5);
                a6 = fmaf(hk, f3.x, a6); a7 = fmaf(hk, f3.y, a7);
            }
            // phase 3: streamed rows 20-49
            const u16* wp = wstream;
            #pragma unroll 10
            for (int i = 0; i < 30; ++i) {
                float hk = hs[20 + i];
                uint4 wv = *(const uint4*)wp;
                wp += 1200;
                float2 f0 = __half22float2(*(__half2*)&wv.x);
                float2 f1 = __half22float2(*(__half2*)&wv.y);
                float2 f2 = __half22float2(*(__half2*)&wv.z);
                float2 f3 = __half22float2(*(__half2*)&wv.w);
                a0 = fmaf(hk, f0.x, a0); a1 = fmaf(hk, f0.y, a1);
                a2 = fmaf(hk, f1.x, a2); a3 = fmaf(hk, f1.y, a3);
                a4 = fmaf(hk, f2.x, a4); a5 = fmaf(hk, f2.y, a5);
                a6 = fmaf(hk, f3.x, a6); a7 = fmaf(hk, f3.y, a7);
            }
            float* pp = &part[g6][8 * u];
            float4 w0 = {a0, a1, a2, a3};
            float4 w1 = {a4, a5, a6, a7};
            *(float4*)pp = w0;
            *(float4*)(pp + 4) = w1;
        }
        __syncthreads();
        if (tid < 300) {
            const float* xr = dir ? (xb + (size_t)(b * rpb + pos - base_b) * ldx)
                                  : (xf + (size_t)(b * rpb + pos - base_f) * ldx);
            float gi = xr[tid], gf = xr[300 + tid], gg = xr[600 + tid], go = xr[900 + tid];
            #pragma unroll
            for (int g = 0; g < 6; ++g) {
                gi += part[g][tid];
                gf += part[g][300 + tid];
                gg += part[g][600 + tid];
                go += part[g][900 + tid];
            }
            gi = sigm(gi); gf = sigm(gf); gg = tanhf(gg); go = sigm(go);
            c = gf * c + gi * gg;
            float hn = go * tanhf(c);
            out[((size_t)b * T + pos) * 600 + dir * 300 + tid] = hn;
            h_s[tid] = hn;
        }
        __syncthreads();
    }
    if (tid < 300) {
        hst[(size_t)blk * 300 + tid] = h_s[tid];
        cst[(size_t)blk * 300 + tid] = c;
    }
}

// ---------------- fused scores+softmax+tgate+mid+cat ----------------
__global__ __launch_bounds__(128) void k_scoremid(
    const float* __restrict__ v, const float* __restrict__ e,
    const int* __restrict__ text, const int* __restrict__ asp,
    const float* __restrict__ l2w, const float* __restrict__ l2b, int iter,
    int rowoff, float* __restrict__ tg,
    u16* __restrict__ cat_hi, u16* __restrict__ cat_lo)
{
    __shared__ float vs[600];
    __shared__ float red[2][9];
    __shared__ float alpha_s[8];
    int row = rowoff + blockIdx.x;
    int rl = blockIdx.x;
    int b = row >> 7;
    int t = threadIdx.x, wv = t >> 6, lane = t & 63;
    const float* vrow = v + (size_t)row * 600;
    const float* eb = e + (size_t)b * 4800;
    const float* w2 = l2w + iter * 600;

    for (int d = t; d < 600; d += 128) vs[d] = vrow[d];
    __syncthreads();

    float acc[9];
    #pragma unroll
    for (int j = 0; j < 9; ++j) acc[j] = 0.f;
    for (int d = t; d < 600; d += 128) {
        float vv = vs[d];
        #pragma unroll
        for (int a = 0; a < 8; ++a) acc[a] += vv * eb[a * 600 + d];
        acc[8] += vv * w2[d];
    }
    #pragma unroll
    for (int off = 32; off >= 1; off >>= 1) {
        #pragma unroll
        for (int j = 0; j < 9; ++j) acc[j] += __shfl_down(acc[j], off, 64);
    }
    if (lane == 0) {
        #pragma unroll
        for (int j = 0; j < 9; ++j) red[wv][j] = acc[j];
    }
    __syncthreads();
    if (t == 0) {
        float dots[9];
        #pragma unroll
        for (int j = 0; j < 9; ++j) dots[j] = red[0][j] + red[1][j];
        tg[row] = sigm(dots[8] + l2b[iter]);
        bool sm = (text[row] != 0);
        float sc[8]; float mx = -INFINITY;
        #pragma unroll
        for (int a = 0; a < 8; ++a) {
            sc[a] = (sm && asp[b * 8 + a] != 0) ? dots[a] : NEGV;
            mx = fmaxf(mx, sc[a]);
        }
        float den = 0.f;
        #pragma unroll
        for (int a = 0; a < 8; ++a) { sc[a] = expf(sc[a] - mx); den += sc[a]; }
        float inv = 1.f / den;
        #pragma unroll
        for (int a = 0; a < 8; ++a) alpha_s[a] = sc[a] * inv;
    }
    __syncthreads();
    for (int d = t; d < 1216; d += 128) {
        float val;
        if (d < 600) {
            float m = 0.f;
            #pragma unroll
            for (int a = 0; a < 8; ++a) m += alpha_s[a] * eb[a * 600 + d];
            val = m;
        } else if (d < 1200) {
            val = vs[d - 600];
        } else {
            val = 0.f;
        }
        u16 hi = f2bf(val);
        cat_hi[(size_t)rl * 1216 + d] = hi;
        cat_lo[(size_t)rl * 1216 + d] = f2bf(val - bf2f(hi));
    }
}

// ---------------- final ----------------
__global__ void k_query(const float* __restrict__ e, const int* __restrict__ asp,
                        float* __restrict__ q) {
    int i = blockIdx.x * 256 + threadIdx.x;
    if (i >= 64 * 600) return;
    int b = i / 600, d = i - b * 600;
    float m = NEGV;
    for (int a = 0; a < 8; ++a)
        if (asp[b * 8 + a] != 0) m = fmaxf(m, e[(size_t)b * 4800 + a * 600 + d]);
    q[i] = m;
}

__global__ __launch_bounds__(128) void k_final(
    const float* __restrict__ v, const float* __restrict__ q,
    const int* __restrict__ text, const float* __restrict__ fcW,
    const float* __restrict__ fcb, const int* __restrict__ flag, void* __restrict__ outv)
{
    __shared__ float red[128];
    __shared__ float al[128];
    __shared__ float zz[600];
    int b = blockIdx.x, s = threadIdx.x;
    const float* vrow = v + (size_t)(b * 128 + s) * 600;
    const float* qb = q + (size_t)b * 600;
    float sc = 0.f;
    for (int d = 0; d < 600; ++d) sc += vrow[d] * qb[d];
    if (text[b * 128 + s] == 0) sc = NEGV;
    red[s] = sc; __syncthreads();
    for (int off = 64; off >= 1; off >>= 1) {
        if (s < off) red[s] = fmaxf(red[s], red[s + off]);
        __syncthreads();
    }
    float mx = red[0]; __syncthreads();
    float ex = expf(sc - mx);
    red[s] = ex; __syncthreads();
    for (int off = 64; off >= 1; off >>= 1) {
        if (s < off) red[s] += red[s + off];
        __syncthreads();
    }
    float alpha = ex / red[0];
    al[s] = alpha; __syncthreads();
    for (int d = s; d < 600; d += 128) {
        float z = 0.f;
        for (int s2 = 0; s2 < 128; ++s2) z += al[s2] * v[(size_t)(b * 128 + s2) * 600 + d];
        zz[d] = z;
    }
    __syncthreads();
    if (s < 3) {
        float o = 0.f;
        for (int d = 0; d < 600; ++d) o += zz[d] * fcW[s * 600 + d];
        o += fcb[s];
        if (*flag) ((float*)outv)[b * 3 + s] = o;
        else       ((u16*)outv)[b * 3 + s] = f2bf(o);
    }
}

// ---------------- host launch ----------------
extern "C" void kernel_launch(void* const* d_in, const int* in_sizes, int n_in,
                              void* d_out, int out_size, void* d_ws, size_t ws_size,
                              hipStream_t stream) {
    const int*  text   = (const int*)d_in[0];
    const int*  asp    = (const int*)d_in[1];
    const void* pw     = d_in[2];
    const void* emb    = d_in[3];
    const void* l1_Wih = d_in[4];
    const void* l1_Whh = d_in[5];
    const void* l1_bih = d_in[6];
    const void* l1_bhh = d_in[7];
    const void* l2_Wih = d_in[8];
    const void* l2_Whh = d_in[9];
    const void* l2_bih = d_in[10];
    const void* l2_bhh = d_in[11];
    const void* lin1_W = d_in[12];
    const void* lin1_b = d_in[13];
    const void* lin2_W = d_in[14];
    const void* lin2_b = d_in[15];
    const void* fcW    = d_in[16];
    const void* fcb    = d_in[17];
    (void)ws_size; (void)n_in; (void)in_sizes; (void)out_size;

    char* w = (char*)d_ws;
    size_t off = 0;
    auto alloc = [&](size_t bytes) -> void* {
        void* p = w + off;
        off += (bytes + 255) & ~(size_t)255;
        return p;
    };
    // ---- persistent (~23 MB) ----
    int*   flag     = (int*)  alloc(4);
    int*   lens     = (int*)  alloc(128ull * 4);
    float* bias_t   = (float*)alloc(2400ull * 4);
    float* bias_a   = (float*)alloc(2400ull * 4);
    float* bias_l1  = (float*)alloc(1280ull * 4);
    float* smallf   = (float*)alloc(11197ull * 4);
    float* tg       = (float*)alloc(8192ull * 4);
    float* query    = (float*)alloc(64ull * 600 * 4);
    float* hst_t    = (float*)alloc(128ull * 300 * 4);
    float* cst_t    = (float*)alloc(128ull * 300 * 4);
    float* hst_a    = (float*)alloc(128ull * 300 * 4);
    float* cst_a    = (float*)alloc(128ull * 300 * 4);
    float* e        = (float*)alloc(512ull * 600 * 4);
    float* v        = (float*)alloc(8192ull * 600 * 4);
    float* pw_f     = smallf;
    float* l2w_f    = smallf + 8192;
    float* l2b_f    = smallf + 9392;
    float* fcW_f    = smallf + 9394;
    float* fcb_f    = smallf + 11194;
    // ---- phase region (union ~32 MB) ----
    size_t phase_off = off;
    // phase A (LSTM)
    u16*   wiht_hi  = (u16*)  alloc(2432ull * 320 * 2);
    u16*   wiht_lo  = (u16*)  alloc(2432ull * 320 * 2);
    u16*   wiha_hi  = (u16*)  alloc(2432ull * 320 * 2);
    u16*   wiha_lo  = (u16*)  alloc(2432ull * 320 * 2);
    u16*   whhT_t   = (u16*)  alloc(720000ull * 2);   // fp16
    u16*   whhT_a   = (u16*)  alloc(720000ull * 2);   // fp16
    float* xf       = (float*)alloc(2048ull * 1200 * 4);
    float* xb       = (float*)alloc(2048ull * 1200 * 4);
    float* xproj_a  = (float*)alloc(512ull * 2400 * 4);
    // phase B (attention) aliases phase A
    off = phase_off;
    u16*   l1w_hi   = (u16*)  alloc(2ull * 640 * 1216 * 2);
    u16*   l1w_lo   = (u16*)  alloc(2ull * 640 * 1216 * 2);
    u16*   cat_hi   = (u16*)  alloc(4096ull * 1216 * 2);
    u16*   cat_lo   = (u16*)  alloc(4096ull * 1216 * 2);

    hipMemsetAsync(v, 0, 8192ull * 600 * 4, stream);
    hipMemsetAsync(e, 0, 512ull * 600 * 4, stream);

    // ---- prep (merged) ----
    k_detect<<<1, 256, 0, stream>>>(emb, flag);
    k_prep_small<<<1, 128, 0, stream>>>(text, asp, lens);
    k_pad_wih2<<<(2 * 2432 * 320 + 255) / 256, 256, 0, stream>>>(
        l1_Wih, l2_Wih, flag, wiht_hi, wiht_lo, wiha_hi, wiha_lo);
    k_whhT2<<<(2 * 720000 + 255) / 256, 256, 0, stream>>>(
        l1_Whh, l2_Whh, flag, whhT_t, whhT_a);
    k_small<<<49, 256, 0, stream>>>(pw, lin2_W, lin2_b, fcW, fcb, lin1_b,
                                    l1_bih, l1_bhh, l2_bih, l2_bhh, flag,
                                    smallf, bias_l1, bias_t, bias_a);

    // ---- aspect xproj (fused gather; consumed by chunk-0 lstm dispatch) ----
    gemm_emb<<<dim3(8, 38), 256, 0, stream>>>(emb, asp, 0, 8, 8, flag,
        wiha_hi, wiha_lo, bias_a, xproj_a, 2400, 2400);

    // ---- text path: 4 chunks of 32 positions; chunk 0 carries aspect chains ----
    for (int kk = 0; kk < 4; ++kk) {
        int bf = 32 * kk;          // fwd base
        int bb = 96 - 32 * kk;     // bwd base (descending consumption)
        gemm_emb<<<dim3(32, 19), 256, 0, stream>>>(emb, text, bf, 32, 128, flag,
            wiht_hi, wiht_lo, bias_t, xf, 1200, 1200);
        gemm_emb<<<dim3(32, 19), 256, 0, stream>>>(emb, text, bb, 32, 128, flag,
            wiht_hi + 1200ull * 320, wiht_lo + 1200ull * 320, bias_t + 1200,
            xb, 1200, 1200);
        int nblk = (kk == 0) ? 256 : 128;
        k_lstm5<<<nblk, 960, 0, stream>>>(xf, xb, 1200, 32, bf, bb,
            whhT_t, lens, v, 128, kk == 0 ? 1 : 0, hst_t, cst_t, 32,
            xproj_a, whhT_a, lens + 64, e, hst_a, cst_a);
    }

    // ---- phase B prep (after last phase-A consumer) ----
    k_pad_lin1<<<(2 * 640 * 1216 + 255) / 256, 256, 0, stream>>>(lin1_W, flag,
                                                                 l1w_hi, l1w_lo);

    // ---- two attention iterations (2 chunks of 4096 rows, fused scoremid) ----
    for (int iter = 0; iter < 2; ++iter) {
        for (int c = 0; c < 2; ++c) {
            int rowoff = c * 4096;
            k_scoremid<<<4096, 128, 0, stream>>>(v, e, text, asp, l2w_f, l2b_f,
                iter, rowoff, tg, cat_hi, cat_lo);
            gemm_bt<<<dim3(64, 10), 256, 0, stream>>>(cat_hi, cat_lo, 1216,
                l1w_hi + (size_t)iter * 640 * 1216, l1w_lo + (size_t)iter * 640 * 1216,
                1216, bias_l1 + iter * 640, 600, 1216,
                tg, pw_f, v, rowoff);
        }
    }

    // ---- final ----
    k_query<<<150, 256, 0, stream>>>(e, asp, query);
    k_final<<<64, 128, 0, stream>>>(v, query, text, fcW_f, fcb_f, flag, d_out);
}

// Round 12
// 1771.387 us; speedup vs baseline: 1.2917x; 1.2917x over previous
//
#include <hip/hip_runtime.h>
#include <hip/hip_bf16.h>
#include <hip/hip_fp16.h>

// RepWalk on MI355X (gfx950). Inputs fp32, output fp32 (verified r4).
// Round 12: r11's VGPR weight cache spilled to scratch (VGPR stuck at 64,
// WRITE_SIZE x8) -> reverted to r10's k_lstm4 structure. New: next-chunk
// xproj GEMM fused into the LSTM dispatch as tail blocks (the LSTM only
// occupies half the chip), writing fp16 xproj into a double buffer consumed
// by the NEXT dispatch. Deletes 6 serial gemm dispatches.

typedef unsigned short u16;
typedef __attribute__((ext_vector_type(8))) short short8;
typedef __attribute__((ext_vector_type(4))) float floatx4;

#define NEGV -1e9f
#define MFMA __builtin_amdgcn_mfma_f32_16x16x32_bf16

__device__ __forceinline__ float bf2f(u16 u) {
    union { unsigned int i; float f; } x; x.i = ((unsigned int)u) << 16; return x.f;
}
__device__ __forceinline__ u16 f2bf(float f) {
    unsigned int u = __float_as_uint(f);
    unsigned int r = (u + 0x7fff + ((u >> 16) & 1)) >> 16;
    return (u16)r;
}
__device__ __forceinline__ float h16(u16 u) {
    __half h; *(u16*)&h = u; return __half2float(h);
}
__device__ __forceinline__ u16 f16(float f) {
    __half h = __float2half(f); return *(u16*)&h;
}
__device__ __forceinline__ float sigm(float x) { return 1.f / (1.f + expf(-x)); }
__device__ __forceinline__ float rdf(const void* p, size_t i, int flag) {
    return flag ? ((const float*)p)[i] : bf2f(((const u16*)p)[i]);
}

// ---------------- dtype detect ----------------
__global__ void k_detect(const void* __restrict__ emb, int* __restrict__ flag) {
    __shared__ int cnt;
    if (threadIdx.x == 0) cnt = 0;
    __syncthreads();
    u16 x = ((const u16*)emb)[4096 + threadIdx.x];
    int e = (x >> 7) & 0xFF;
    if (e >= 0x8A) atomicAdd(&cnt, 1);
    __syncthreads();
    if (threadIdx.x == 0) *flag = (cnt > 8) ? 1 : 0;
}

// ---------------- small prep ----------------
__global__ void k_prep_small(const int* __restrict__ text, const int* __restrict__ asp,
                             int* __restrict__ lens) {
    int tid = threadIdx.x;
    if (tid < 64) {
        int c = 0;
        for (int s = 0; s < 128; ++s) c += (text[tid * 128 + s] != 0);
        lens[tid] = c;
    } else if (tid < 128) {
        int b = tid - 64; int c = 0;
        for (int a = 0; a < 8; ++a) c += (asp[b * 8 + a] != 0);
        lens[64 + b] = c;
    }
}

// both Wih layers -> padded [2432,320] hi/lo each
__global__ void k_pad_wih2(const void* __restrict__ W1, const void* __restrict__ W2,
                           const int* __restrict__ flag,
                           u16* __restrict__ d1h, u16* __restrict__ d1l,
                           u16* __restrict__ d2h, u16* __restrict__ d2l) {
    int i = blockIdx.x * 256 + threadIdx.x;
    if (i >= 2 * 2432 * 320) return;
    int f = *flag;
    int layer = i / (2432 * 320), r = i - layer * (2432 * 320);
    int n = r / 320, k = r - n * 320;
    const void* W = layer ? W2 : W1;
    float val = (n < 2400 && k < 300) ? rdf(W, (size_t)n * 300 + k, f) : 0.f;
    u16 hi = f2bf(val);
    float lo = val - bf2f(hi);
    if (layer) { d2h[r] = hi; d2l[r] = f2bf(lo); }
    else       { d1h[r] = hi; d1l[r] = f2bf(lo); }
}

// both Whh layers -> WhhT fp16 [2,300,1200] each
__global__ void k_whhT2(const void* __restrict__ W1, const void* __restrict__ W2,
                        const int* __restrict__ flag,
                        u16* __restrict__ d1, u16* __restrict__ d2) {
    int i = blockIdx.x * 256 + threadIdx.x;
    if (i >= 2 * 720000) return;
    int f = *flag;
    int layer = i / 720000, r = i - layer * 720000;
    int dir = r / 360000, rr = r - dir * 360000;
    int k = rr / 1200, g = rr - k * 1200;
    const void* W = layer ? W2 : W1;
    u16 bits = f16(rdf(W, (size_t)dir * 360000 + (size_t)g * 300 + k, f));
    if (layer) d2[r] = bits; else d1[r] = bits;
}

// lin1_W [2,600,1200] -> padded [2,640,1216] hi/lo
__global__ void k_pad_lin1(const void* __restrict__ W, const int* __restrict__ flag,
                           u16* __restrict__ dhi, u16* __restrict__ dlo) {
    int i = blockIdx.x * 256 + threadIdx.x;
    if (i >= 2 * 640 * 1216) return;
    int f = *flag;
    int dir = i / (640 * 1216), r = i - dir * (640 * 1216);
    int n = r / 1216, k = r - n * 1216;
    float val = (n < 600 && k < 1200)
        ? rdf(W, (size_t)dir * 720000 + (size_t)n * 1200 + k, f) : 0.f;
    u16 hi = f2bf(val);
    dhi[i] = hi;
    dlo[i] = f2bf(val - bf2f(hi));
}

// smallf = pw(8192)|l2w(1200)|l2b(2)|fcw(1800)|fcb(3); bl[1280]; bias_t/a[2400]
__global__ void k_small(const void* pw, const void* l2w, const void* l2b,
                        const void* fcw, const void* fcb, const void* lb,
                        const void* b1i, const void* b1h, const void* b2i, const void* b2h,
                        const int* __restrict__ flag,
                        float* __restrict__ dst, float* __restrict__ bl,
                        float* __restrict__ bt, float* __restrict__ ba) {
    int i = blockIdx.x * 256 + threadIdx.x;
    int f = *flag;
    if (i < 8192)            dst[i] = rdf(pw, i, f);
    else if (i < 9392)       dst[i] = rdf(l2w, i - 8192, f);
    else if (i < 9394)       dst[i] = rdf(l2b, i - 9392, f);
    else if (i < 11194)      dst[i] = rdf(fcw, i - 9394, f);
    else if (i < 11197)      dst[i] = rdf(fcb, i - 11194, f);
    if (i < 1280) {
        int dir = i / 640, c = i - dir * 640;
        bl[i] = (c < 600) ? rdf(lb, dir * 600 + c, f) : 0.f;
    }
    if (i < 2400) {
        bt[i] = rdf(b1i, i, f) + rdf(b1h, i, f);
        ba[i] = rdf(b2i, i, f) + rdf(b2h, i, f);
    }
}

// ---------------- shared gather-GEMM tile (fp16 output) ----------------
// C[64x64 tile at (bx,by)] = gather(emb)[M,300p320] @ (Bhi+Blo)[N,320]^T + bias
__device__ __forceinline__ void gemm_emb_tile(
    const void* __restrict__ emb, const int* __restrict__ ids,
    int base, int rpb, int stride, int f,
    const u16* __restrict__ Bhi, const u16* __restrict__ Blo,
    const float* __restrict__ bias,
    u16* __restrict__ C, int ldc, int nstore, int bx, int by, int tid)
{
    int wave = tid >> 6, lane = tid & 63;
    int l15 = lane & 15, quad = lane >> 4;
    int m0 = bx * 64 + wave * 16;
    int n0 = by * 64;

    int m = m0 + l15;
    int b = m / rpb, j = m - b * rpb;
    int id = ids[b * stride + base + j];
    const float* arow_f = (const float*)emb + (size_t)id * 300;
    const u16*   arow_b = (const u16*)emb + (size_t)id * 300;

    const u16* Bp  = Bhi + (size_t)(n0 + l15) * 320 + quad * 8;
    const u16* Bp2 = Blo + (size_t)(n0 + l15) * 320 + quad * 8;

    floatx4 acc0 = {0.f, 0.f, 0.f, 0.f};
    floatx4 acc1 = acc0, acc2 = acc0, acc3 = acc0;

    for (int kc = 0; kc < 10; ++kc) {
        int ko = kc * 32 + quad * 8;
        short8 ahi, alo;
        if (f) {
            if (ko + 8 <= 300) {
                float4 fa = *(const float4*)(arow_f + ko);
                float4 fb = *(const float4*)(arow_f + ko + 4);
                float vv[8] = {fa.x, fa.y, fa.z, fa.w, fb.x, fb.y, fb.z, fb.w};
                #pragma unroll
                for (int t = 0; t < 8; ++t) {
                    u16 h = f2bf(vv[t]);
                    ahi[t] = (short)h;
                    alo[t] = (short)f2bf(vv[t] - bf2f(h));
                }
            } else {
                #pragma unroll
                for (int t = 0; t < 8; ++t) {
                    int k = ko + t;
                    float vv = (k < 300) ? arow_f[k] : 0.f;
                    u16 h = f2bf(vv);
                    ahi[t] = (short)h;
                    alo[t] = (short)f2bf(vv - bf2f(h));
                }
            }
        } else {
            #pragma unroll
            for (int t = 0; t < 8; ++t) {
                int k = ko + t;
                ahi[t] = (k < 300) ? (short)arow_b[k] : (short)0;
                alo[t] = 0;
            }
        }
        int ko2 = kc * 32;
        short8 bh0 = *(const short8*)(Bp + ko2);
        short8 bh1 = *(const short8*)(Bp + (size_t)16 * 320 + ko2);
        short8 bh2 = *(const short8*)(Bp + (size_t)32 * 320 + ko2);
        short8 bh3 = *(const short8*)(Bp + (size_t)48 * 320 + ko2);
        short8 bl0 = *(const short8*)(Bp2 + ko2);
        short8 bl1 = *(const short8*)(Bp2 + (size_t)16 * 320 + ko2);
        short8 bl2 = *(const short8*)(Bp2 + (size_t)32 * 320 + ko2);
        short8 bl3 = *(const short8*)(Bp2 + (size_t)48 * 320 + ko2);
        acc0 = MFMA(ahi, bh0, acc0, 0, 0, 0);
        acc1 = MFMA(ahi, bh1, acc1, 0, 0, 0);
        acc2 = MFMA(ahi, bh2, acc2, 0, 0, 0);
        acc3 = MFMA(ahi, bh3, acc3, 0, 0, 0);
        acc0 = MFMA(ahi, bl0, acc0, 0, 0, 0);
        acc1 = MFMA(ahi, bl1, acc1, 0, 0, 0);
        acc2 = MFMA(ahi, bl2, acc2, 0, 0, 0);
        acc3 = MFMA(ahi, bl3, acc3, 0, 0, 0);
        acc0 = MFMA(alo, bh0, acc0, 0, 0, 0);
        acc1 = MFMA(alo, bh1, acc1, 0, 0, 0);
        acc2 = MFMA(alo, bh2, acc2, 0, 0, 0);
        acc3 = MFMA(alo, bh3, acc3, 0, 0, 0);
    }

    #pragma unroll
    for (int c = 0; c < 4; ++c) {
        floatx4 acc = (c == 0) ? acc0 : (c == 1) ? acc1 : (c == 2) ? acc2 : acc3;
        int col = n0 + c * 16 + l15;
        if (col >= nstore) continue;
        float bb = bias[col];
        #pragma unroll
        for (int r = 0; r < 4; ++r) {
            int row = m0 + quad * 4 + r;
            C[(size_t)row * ldc + col] = f16(acc[r] + bb);
        }
    }
}

__global__ __launch_bounds__(256) void gemm_embk(
    const void* __restrict__ emb, const int* __restrict__ ids,
    int base, int rpb, int stride, const int* __restrict__ flag,
    const u16* __restrict__ Bhi, const u16* __restrict__ Blo,
    const float* __restrict__ bias,
    u16* __restrict__ C, int ldc, int nstore)
{
    gemm_emb_tile(emb, ids, base, rpb, stride, *flag, Bhi, Blo, bias,
                  C, ldc, nstore, blockIdx.x, blockIdx.y, threadIdx.x);
}

// ---------------- MFMA GEMM (lin1): fused epilogue ----------------
__global__ __launch_bounds__(256) void gemm_bt(
    const u16* __restrict__ Ahi, const u16* __restrict__ Alo, int lda,
    const u16* __restrict__ Bhi, const u16* __restrict__ Blo, int ldb,
    const float* __restrict__ bias,
    int nstore, int K,
    const float* __restrict__ tg, const float* __restrict__ pw, float* __restrict__ vio,
    int mrowoff)
{
    int tid = threadIdx.x;
    int wave = tid >> 6, lane = tid & 63;
    int l15 = lane & 15, quad = lane >> 4;
    int m0 = blockIdx.x * 64 + wave * 16;
    int n0 = blockIdx.y * 64;

    const u16* Ap  = Ahi + (size_t)(m0 + l15) * lda + quad * 8;
    const u16* Ap2 = Alo + (size_t)(m0 + l15) * lda + quad * 8;
    const u16* Bp  = Bhi + (size_t)(n0 + l15) * ldb + quad * 8;
    const u16* Bp2 = Blo + (size_t)(n0 + l15) * ldb + quad * 8;

    floatx4 acc0 = {0.f, 0.f, 0.f, 0.f};
    floatx4 acc1 = acc0, acc2 = acc0, acc3 = acc0;

    int nk = K >> 5;
    for (int kc = 0; kc < nk; ++kc) {
        int ko = kc * 32;
        short8 bh0 = *(const short8*)(Bp + ko);
        short8 bh1 = *(const short8*)(Bp + (size_t)16 * ldb + ko);
        short8 bh2 = *(const short8*)(Bp + (size_t)32 * ldb + ko);
        short8 bh3 = *(const short8*)(Bp + (size_t)48 * ldb + ko);
        short8 bl0 = *(const short8*)(Bp2 + ko);
        short8 bl1 = *(const short8*)(Bp2 + (size_t)16 * ldb + ko);
        short8 bl2 = *(const short8*)(Bp2 + (size_t)32 * ldb + ko);
        short8 bl3 = *(const short8*)(Bp2 + (size_t)48 * ldb + ko);
        short8 a  = *(const short8*)(Ap + ko);
        short8 al = *(const short8*)(Ap2 + ko);
        acc0 = MFMA(a, bh0, acc0, 0, 0, 0);
        acc1 = MFMA(a, bh1, acc1, 0, 0, 0);
        acc2 = MFMA(a, bh2, acc2, 0, 0, 0);
        acc3 = MFMA(a, bh3, acc3, 0, 0, 0);
        acc0 = MFMA(a, bl0, acc0, 0, 0, 0);
        acc1 = MFMA(a, bl1, acc1, 0, 0, 0);
        acc2 = MFMA(a, bl2, acc2, 0, 0, 0);
        acc3 = MFMA(a, bl3, acc3, 0, 0, 0);
        acc0 = MFMA(al, bh0, acc0, 0, 0, 0);
        acc1 = MFMA(al, bh1, acc1, 0, 0, 0);
        acc2 = MFMA(al, bh2, acc2, 0, 0, 0);
        acc3 = MFMA(al, bh3, acc3, 0, 0, 0);
    }

    #pragma unroll
    for (int c = 0; c < 4; ++c) {
        floatx4 acc = (c == 0) ? acc0 : (c == 1) ? acc1 : (c == 2) ? acc2 : acc3;
        int col = n0 + c * 16 + l15;
        if (col >= nstore) continue;
        float bb = bias[col];
        #pragma unroll
        for (int r = 0; r < 4; ++r) {
            int row = m0 + quad * 4 + r;
            float val = acc[r] + bb;
            val = val > 0.f ? val : 0.01f * val;      // leaky_relu
            int rg = row + mrowoff;
            float t = tg[rg];
            size_t vi = (size_t)rg * 600 + col;
            float vv = vio[vi];
            vio[vi] = pw[rg] * ((1.f - t) * val + t * vv);
        }
    }
}

// ---------------- fused LSTM + next-chunk xproj GEMM ----------------
// blocks [0,128): text chains (chunk kk). [128,nLstm): aspect chains (kk==0).
// [nLstm, nLstm+1216): 64x64 gemm tiles for chunk kk+1 (fwd 608 then bwd 608),
// 256 active threads, writing fp16 xproj into the other double buffer.
__global__ __launch_bounds__(960, 1) void k_lstm6(
    const u16* __restrict__ xf, const u16* __restrict__ xb, int ldx, int rpb,
    int base_f, int base_b, const u16* __restrict__ whhT,
    const int* __restrict__ lens, float* __restrict__ out, int T, int init,
    float* __restrict__ hst, float* __restrict__ cst, int nsteps,
    const u16* __restrict__ xa, const u16* __restrict__ whhA,
    const int* __restrict__ lensA, float* __restrict__ outA,
    float* __restrict__ hstA, float* __restrict__ cstA, int nLstm,
    const void* __restrict__ emb, const int* __restrict__ text,
    int bf_next, int bb_next, const int* __restrict__ flag,
    const u16* __restrict__ wih_hi, const u16* __restrict__ wih_lo,
    const float* __restrict__ bias_t,
    u16* __restrict__ xf_next, u16* __restrict__ xb_next)
{
    __shared__ float h_s[300];
    __shared__ float part[6][1200];
    int blk = blockIdx.x;
    if (blk >= nLstm) {                   // next-chunk gemm tile
        if (threadIdx.x >= 256) return;
        int g = blk - nLstm;
        int dirn = g / 608; int t = g - dirn * 608;
        int bx = t & 31, by = t >> 5;     // 32 x 19
        gemm_emb_tile(emb, text, dirn ? bb_next : bf_next, 32, 128, *flag,
                      wih_hi + (dirn ? 1200ull * 320 : 0),
                      wih_lo + (dirn ? 1200ull * 320 : 0),
                      bias_t + (dirn ? 1200 : 0),
                      dirn ? xb_next : xf_next, 1200, 1200, bx, by, threadIdx.x);
        return;
    }
    if (blk >= 128) {                     // fused aspect chain
        blk -= 128;
        xf = xa; xb = xa + 1200; ldx = 2400; rpb = 8;
        base_f = 0; base_b = 0;
        whhT = whhA; lens = lensA; out = outA; T = 8; init = 1;
        hst = hstA; cst = cstA; nsteps = 8;
    }
    int tid = threadIdx.x;
    int g6 = tid / 160, u = tid - g6 * 160;
    bool act = (u < 150);
    int b = blk >> 1, dir = blk & 1;
    int len = lens[b];
    float c = 0.f;
    if (tid < 300) {
        h_s[tid] = init ? 0.f : hst[(size_t)blk * 300 + tid];
        c = init ? 0.f : cst[(size_t)blk * 300 + tid];
    }
    __syncthreads();
    const u16* wbase = whhT + (size_t)dir * 360000 + (size_t)g6 * 50 * 1200 + 8 * u;

    for (int s = 0; s < nsteps; ++s) {
        int pos = dir ? (base_b + nsteps - 1 - s) : (base_f + s);
        if (pos >= len) continue;           // block-uniform skip
        if (act) {
            float a0 = 0.f, a1 = 0.f, a2 = 0.f, a3 = 0.f;
            float a4 = 0.f, a5 = 0.f, a6 = 0.f, a7 = 0.f;
            const u16* wp = wbase;
            const float* hs = h_s + g6 * 50;
            #pragma unroll 10
            for (int i = 0; i < 50; ++i) {
                float hk = hs[i];
                uint4 wv = *(const uint4*)wp;
                wp += 1200;
                float2 f0 = __half22float2(*(__half2*)&wv.x);
                float2 f1 = __half22float2(*(__half2*)&wv.y);
                float2 f2 = __half22float2(*(__half2*)&wv.z);
                float2 f3 = __half22float2(*(__half2*)&wv.w);
                a0 = fmaf(hk, f0.x, a0); a1 = fmaf(hk, f0.y, a1);
                a2 = fmaf(hk, f1.x, a2); a3 = fmaf(hk, f1.y, a3);
                a4 = fmaf(hk, f2.x, a4); a5 = fmaf(hk, f2.y, a5);
                a6 = fmaf(hk, f3.x, a6); a7 = fmaf(hk, f3.y, a7);
            }
            float* pp = &part[g6][8 * u];
            float4 w0 = {a0, a1, a2, a3};
            float4 w1 = {a4, a5, a6, a7};
            *(float4*)pp = w0;
            *(float4*)(pp + 4) = w1;
        }
        __syncthreads();
        if (tid < 300) {
            const u16* xr = dir ? (xb + (size_t)(b * rpb + pos - base_b) * ldx)
                                : (xf + (size_t)(b * rpb + pos - base_f) * ldx);
            float gi = h16(xr[tid]), gf = h16(xr[300 + tid]);
            float gg = h16(xr[600 + tid]), go = h16(xr[900 + tid]);
            #pragma unroll
            for (int g = 0; g < 6; ++g) {
                gi += part[g][tid];
                gf += part[g][300 + tid];
                gg += part[g][600 + tid];
                go += part[g][900 + tid];
            }
            gi = sigm(gi); gf = sigm(gf); gg = tanhf(gg); go = sigm(go);
            c = gf * c + gi * gg;
            float hn = go * tanhf(c);
            out[((size_t)b * T + pos) * 600 + dir * 300 + tid] = hn;
            h_s[tid] = hn;
        }
        __syncthreads();
    }
    if (tid < 300) {
        hst[(size_t)blk * 300 + tid] = h_s[tid];
        cst[(size_t)blk * 300 + tid] = c;
    }
}

// ---------------- fused scores+softmax+tgate+mid+cat ----------------
__global__ __launch_bounds__(128) void k_scoremid(
    const float* __restrict__ v, const float* __restrict__ e,
    const int* __restrict__ text, const int* __restrict__ asp,
    const float* __restrict__ l2w, const float* __restrict__ l2b, int iter,
    int rowoff, float* __restrict__ tg,
    u16* __restrict__ cat_hi, u16* __restrict__ cat_lo)
{
    __shared__ float vs[600];
    __shared__ float red[2][9];
    __shared__ float alpha_s[8];
    int row = rowoff + blockIdx.x;
    int rl = blockIdx.x;
    int b = row >> 7;
    int t = threadIdx.x, wv = t >> 6, lane = t & 63;
    const float* vrow = v + (size_t)row * 600;
    const float* eb = e + (size_t)b * 4800;
    const float* w2 = l2w + iter * 600;

    for (int d = t; d < 600; d += 128) vs[d] = vrow[d];
    __syncthreads();

    float acc[9];
    #pragma unroll
    for (int j = 0; j < 9; ++j) acc[j] = 0.f;
    for (int d = t; d < 600; d += 128) {
        float vv = vs[d];
        #pragma unroll
        for (int a = 0; a < 8; ++a) acc[a] += vv * eb[a * 600 + d];
        acc[8] += vv * w2[d];
    }
    #pragma unroll
    for (int off = 32; off >= 1; off >>= 1) {
        #pragma unroll
        for (int j = 0; j < 9; ++j) acc[j] += __shfl_down(acc[j], off, 64);
    }
    if (lane == 0) {
        #pragma unroll
        for (int j = 0; j < 9; ++j) red[wv][j] = acc[j];
    }
    __syncthreads();
    if (t == 0) {
        float dots[9];
        #pragma unroll
        for (int j = 0; j < 9; ++j) dots[j] = red[0][j] + red[1][j];
        tg[row] = sigm(dots[8] + l2b[iter]);
        bool sm = (text[row] != 0);
        float sc[8]; float mx = -INFINITY;
        #pragma unroll
        for (int a = 0; a < 8; ++a) {
            sc[a] = (sm && asp[b * 8 + a] != 0) ? dots[a] : NEGV;
            mx = fmaxf(mx, sc[a]);
        }
        float den = 0.f;
        #pragma unroll
        for (int a = 0; a < 8; ++a) { sc[a] = expf(sc[a] - mx); den += sc[a]; }
        float inv = 1.f / den;
        #pragma unroll
        for (int a = 0; a < 8; ++a) alpha_s[a] = sc[a] * inv;
    }
    __syncthreads();
    for (int d = t; d < 1216; d += 128) {
        float val;
        if (d < 600) {
            float m = 0.f;
            #pragma unroll
            for (int a = 0; a < 8; ++a) m += alpha_s[a] * eb[a * 600 + d];
            val = m;
        } else if (d < 1200) {
            val = vs[d - 600];
        } else {
            val = 0.f;
        }
        u16 hi = f2bf(val);
        cat_hi[(size_t)rl * 1216 + d] = hi;
        cat_lo[(size_t)rl * 1216 + d] = f2bf(val - bf2f(hi));
    }
}

// ---------------- final ----------------
__global__ void k_query(const float* __restrict__ e, const int* __restrict__ asp,
                        float* __restrict__ q) {
    int i = blockIdx.x * 256 + threadIdx.x;
    if (i >= 64 * 600) return;
    int b = i / 600, d = i - b * 600;
    float m = NEGV;
    for (int a = 0; a < 8; ++a)
        if (asp[b * 8 + a] != 0) m = fmaxf(m, e[(size_t)b * 4800 + a * 600 + d]);
    q[i] = m;
}

__global__ __launch_bounds__(128) void k_final(
    const float* __restrict__ v, const float* __restrict__ q,
    const int* __restrict__ text, const float* __restrict__ fcW,
    const float* __restrict__ fcb, const int* __restrict__ flag, void* __restrict__ outv)
{
    __shared__ float red[128];
    __shared__ float al[128];
    __shared__ float zz[600];
    int b = blockIdx.x, s = threadIdx.x;
    const float* vrow = v + (size_t)(b * 128 + s) * 600;
    const float* qb = q + (size_t)b * 600;
    float sc = 0.f;
    for (int d = 0; d < 600; ++d) sc += vrow[d] * qb[d];
    if (text[b * 128 + s] == 0) sc = NEGV;
    red[s] = sc; __syncthreads();
    for (int off = 64; off >= 1; off >>= 1) {
        if (s < off) red[s] = fmaxf(red[s], red[s + off]);
        __syncthreads();
    }
    float mx = red[0]; __syncthreads();
    float ex = expf(sc - mx);
    red[s] = ex; __syncthreads();
    for (int off = 64; off >= 1; off >>= 1) {
        if (s < off) red[s] += red[s + off];
        __syncthreads();
    }
    float alpha = ex / red[0];
    al[s] = alpha; __syncthreads();
    for (int d = s; d < 600; d += 128) {
        float z = 0.f;
        for (int s2 = 0; s2 < 128; ++s2) z += al[s2] * v[(size_t)(b * 128 + s2) * 600 + d];
        zz[d] = z;
    }
    __syncthreads();
    if (s < 3) {
        float o = 0.f;
        for (int d = 0; d < 600; ++d) o += zz[d] * fcW[s * 600 + d];
        o += fcb[s];
        if (*flag) ((float*)outv)[b * 3 + s] = o;
        else       ((u16*)outv)[b * 3 + s] = f2bf(o);
    }
}

// ---------------- host launch ----------------
extern "C" void kernel_launch(void* const* d_in, const int* in_sizes, int n_in,
                              void* d_out, int out_size, void* d_ws, size_t ws_size,
                              hipStream_t stream) {
    const int*  text   = (const int*)d_in[0];
    const int*  asp    = (const int*)d_in[1];
    const void* pw     = d_in[2];
    const void* emb    = d_in[3];
    const void* l1_Wih = d_in[4];
    const void* l1_Whh = d_in[5];
    const void* l1_bih = d_in[6];
    const void* l1_bhh = d_in[7];
    const void* l2_Wih = d_in[8];
    const void* l2_Whh = d_in[9];
    const void* l2_bih = d_in[10];
    const void* l2_bhh = d_in[11];
    const void* lin1_W = d_in[12];
    const void* lin1_b = d_in[13];
    const void* lin2_W = d_in[14];
    const void* lin2_b = d_in[15];
    const void* fcW    = d_in[16];
    const void* fcb    = d_in[17];
    (void)ws_size; (void)n_in; (void)in_sizes; (void)out_size;

    char* w = (char*)d_ws;
    size_t off = 0;
    auto alloc = [&](size_t bytes) -> void* {
        void* p = w + off;
        off += (bytes + 255) & ~(size_t)255;
        return p;
    };
    // ---- persistent (~23 MB) ----
    int*   flag     = (int*)  alloc(4);
    int*   lens     = (int*)  alloc(128ull * 4);
    float* bias_t   = (float*)alloc(2400ull * 4);
    float* bias_a   = (float*)alloc(2400ull * 4);
    float* bias_l1  = (float*)alloc(1280ull * 4);
    float* smallf   = (float*)alloc(11197ull * 4);
    float* tg       = (float*)alloc(8192ull * 4);
    float* query    = (float*)alloc(64ull * 600 * 4);
    float* hst_t    = (float*)alloc(128ull * 300 * 4);
    float* cst_t    = (float*)alloc(128ull * 300 * 4);
    float* hst_a    = (float*)alloc(128ull * 300 * 4);
    float* cst_a    = (float*)alloc(128ull * 300 * 4);
    float* e        = (float*)alloc(512ull * 600 * 4);
    float* v        = (float*)alloc(8192ull * 600 * 4);
    float* pw_f     = smallf;
    float* l2w_f    = smallf + 8192;
    float* l2b_f    = smallf + 9392;
    float* fcW_f    = smallf + 9394;
    float* fcb_f    = smallf + 11194;
    // ---- phase region (union ~31 MB) ----
    size_t phase_off = off;
    // phase A (LSTM)
    u16*   wiht_hi  = (u16*)  alloc(2432ull * 320 * 2);
    u16*   wiht_lo  = (u16*)  alloc(2432ull * 320 * 2);
    u16*   wiha_hi  = (u16*)  alloc(2432ull * 320 * 2);
    u16*   wiha_lo  = (u16*)  alloc(2432ull * 320 * 2);
    u16*   whhT_t   = (u16*)  alloc(720000ull * 2);   // fp16
    u16*   whhT_a   = (u16*)  alloc(720000ull * 2);   // fp16
    u16*   xf0      = (u16*)  alloc(2048ull * 1200 * 2);   // fp16 xproj dbuf
    u16*   xb0      = (u16*)  alloc(2048ull * 1200 * 2);
    u16*   xf1      = (u16*)  alloc(2048ull * 1200 * 2);
    u16*   xb1      = (u16*)  alloc(2048ull * 1200 * 2);
    u16*   xproj_a  = (u16*)  alloc(512ull * 2400 * 2);    // fp16
    // phase B (attention) aliases phase A
    off = phase_off;
    u16*   l1w_hi   = (u16*)  alloc(2ull * 640 * 1216 * 2);
    u16*   l1w_lo   = (u16*)  alloc(2ull * 640 * 1216 * 2);
    u16*   cat_hi   = (u16*)  alloc(4096ull * 1216 * 2);
    u16*   cat_lo   = (u16*)  alloc(4096ull * 1216 * 2);

    hipMemsetAsync(v, 0, 8192ull * 600 * 4, stream);
    hipMemsetAsync(e, 0, 512ull * 600 * 4, stream);

    // ---- prep (merged) ----
    k_detect<<<1, 256, 0, stream>>>(emb, flag);
    k_prep_small<<<1, 128, 0, stream>>>(text, asp, lens);
    k_pad_wih2<<<(2 * 2432 * 320 + 255) / 256, 256, 0, stream>>>(
        l1_Wih, l2_Wih, flag, wiht_hi, wiht_lo, wiha_hi, wiha_lo);
    k_whhT2<<<(2 * 720000 + 255) / 256, 256, 0, stream>>>(
        l1_Whh, l2_Whh, flag, whhT_t, whhT_a);
    k_small<<<49, 256, 0, stream>>>(pw, lin2_W, lin2_b, fcW, fcb, lin1_b,
                                    l1_bih, l1_bhh, l2_bih, l2_bhh, flag,
                                    smallf, bias_l1, bias_t, bias_a);

    // ---- standalone xproj gemms: aspect + chunk 0 (fwd & bwd) ----
    gemm_embk<<<dim3(8, 38), 256, 0, stream>>>(emb, asp, 0, 8, 8, flag,
        wiha_hi, wiha_lo, bias_a, xproj_a, 2400, 2400);
    gemm_embk<<<dim3(32, 19), 256, 0, stream>>>(emb, text, 0, 32, 128, flag,
        wiht_hi, wiht_lo, bias_t, xf0, 1200, 1200);
    gemm_embk<<<dim3(32, 19), 256, 0, stream>>>(emb, text, 96, 32, 128, flag,
        wiht_hi + 1200ull * 320, wiht_lo + 1200ull * 320, bias_t + 1200,
        xb0, 1200, 1200);

    // ---- text path: 4 chunks of 32 positions; each dispatch also computes
    //      the NEXT chunk's xproj on otherwise-idle CUs ----
    for (int kk = 0; kk < 4; ++kk) {
        int bf = 32 * kk;
        int bb = 96 - 32 * kk;
        u16* xfc = (kk & 1) ? xf1 : xf0;
        u16* xbc = (kk & 1) ? xb1 : xb0;
        u16* xfn = (kk & 1) ? xf0 : xf1;
        u16* xbn = (kk & 1) ? xb0 : xb1;
        int nLstm = (kk == 0) ? 256 : 128;
        int haveNext = (kk < 3);
        int nblk = nLstm + (haveNext ? 1216 : 0);
        k_lstm6<<<nblk, 960, 0, stream>>>(xfc, xbc, 1200, 32, bf, bb,
            whhT_t, lens, v, 128, kk == 0 ? 1 : 0, hst_t, cst_t, 32,
            xproj_a, whhT_a, lens + 64, e, hst_a, cst_a, nLstm,
            emb, text, bf + 32, bb - 32, flag, wiht_hi, wiht_lo, bias_t,
            xfn, xbn);
    }

    // ---- phase B prep (after last phase-A consumer) ----
    k_pad_lin1<<<(2 * 640 * 1216 + 255) / 256, 256, 0, stream>>>(lin1_W, flag,
                                                                 l1w_hi, l1w_lo);

    // ---- two attention iterations (2 chunks of 4096 rows, fused scoremid) ----
    for (int iter = 0; iter < 2; ++iter) {
        for (int c = 0; c < 2; ++c) {
            int rowoff = c * 4096;
            k_scoremid<<<4096, 128, 0, stream>>>(v, e, text, asp, l2w_f, l2b_f,
                iter, rowoff, tg, cat_hi, cat_lo);
            gemm_bt<<<dim3(64, 10), 256, 0, stream>>>(cat_hi, cat_lo, 1216,
                l1w_hi + (size_t)iter * 640 * 1216, l1w_lo + (size_t)iter * 640 * 1216,
                1216, bias_l1 + iter * 640, 600, 1216,
                tg, pw_f, v, rowoff);
        }
    }

    // ---- final ----
    k_query<<<150, 256, 0, stream>>>(e, asp, query);
    k_final<<<64, 128, 0, stream>>>(v, query, text, fcW_f, fcb_f, flag, d_out);
}

// Round 13
// 1321.218 us; speedup vs baseline: 1.7319x; 1.3407x over previous
//
#include <hip/hip_runtime.h>
#include <hip/hip_bf16.h>
#include <hip/hip_fp16.h>

// RepWalk on MI355X (gfx950). Inputs fp32, output fp32 (verified r4).
// Round 13:
//  (a) lin1 restructure: cat@W1^T = alpha@(e@W1a^T) + v@W1b^T. EW=e@W1a^T
//      precomputed once; GEMM K 1216->608; cat (40MB/chunk) replaced by a
//      608-col v-split; attention 8 dispatches -> 5, un-chunked.
//  (b) LDS weight cache in LSTM: 8/50 rows per k-group (115KB LDS, no VGPR
//      arrays -> no r11 spill), stream 42 rows. 16% fewer vmem instrs.

typedef unsigned short u16;
typedef __attribute__((ext_vector_type(8))) short short8;
typedef __attribute__((ext_vector_type(4))) float floatx4;

#define NEGV -1e9f
#define MFMA __builtin_amdgcn_mfma_f32_16x16x32_bf16

__device__ __forceinline__ float bf2f(u16 u) {
    union { unsigned int i; float f; } x; x.i = ((unsigned int)u) << 16; return x.f;
}
__device__ __forceinline__ u16 f2bf(float f) {
    unsigned int u = __float_as_uint(f);
    unsigned int r = (u + 0x7fff + ((u >> 16) & 1)) >> 16;
    return (u16)r;
}
__device__ __forceinline__ float h16(u16 u) {
    __half h; *(u16*)&h = u; return __half2float(h);
}
__device__ __forceinline__ u16 f16(float f) {
    __half h = __float2half(f); return *(u16*)&h;
}
__device__ __forceinline__ float sigm(float x) { return 1.f / (1.f + expf(-x)); }
__device__ __forceinline__ float rdf(const void* p, size_t i, int flag) {
    return flag ? ((const float*)p)[i] : bf2f(((const u16*)p)[i]);
}

// ---------------- dtype detect ----------------
__global__ void k_detect(const void* __restrict__ emb, int* __restrict__ flag) {
    __shared__ int cnt;
    if (threadIdx.x == 0) cnt = 0;
    __syncthreads();
    u16 x = ((const u16*)emb)[4096 + threadIdx.x];
    int e = (x >> 7) & 0xFF;
    if (e >= 0x8A) atomicAdd(&cnt, 1);
    __syncthreads();
    if (threadIdx.x == 0) *flag = (cnt > 8) ? 1 : 0;
}

// ---------------- small prep ----------------
__global__ void k_prep_small(const int* __restrict__ text, const int* __restrict__ asp,
                             int* __restrict__ lens) {
    int tid = threadIdx.x;
    if (tid < 64) {
        int c = 0;
        for (int s = 0; s < 128; ++s) c += (text[tid * 128 + s] != 0);
        lens[tid] = c;
    } else if (tid < 128) {
        int b = tid - 64; int c = 0;
        for (int a = 0; a < 8; ++a) c += (asp[b * 8 + a] != 0);
        lens[64 + b] = c;
    }
}

// both Wih layers -> padded [2432,320] hi/lo each
__global__ void k_pad_wih2(const void* __restrict__ W1, const void* __restrict__ W2,
                           const int* __restrict__ flag,
                           u16* __restrict__ d1h, u16* __restrict__ d1l,
                           u16* __restrict__ d2h, u16* __restrict__ d2l) {
    int i = blockIdx.x * 256 + threadIdx.x;
    if (i >= 2 * 2432 * 320) return;
    int f = *flag;
    int layer = i / (2432 * 320), r = i - layer * (2432 * 320);
    int n = r / 320, k = r - n * 320;
    const void* W = layer ? W2 : W1;
    float val = (n < 2400 && k < 300) ? rdf(W, (size_t)n * 300 + k, f) : 0.f;
    u16 hi = f2bf(val);
    float lo = val - bf2f(hi);
    if (layer) { d2h[r] = hi; d2l[r] = f2bf(lo); }
    else       { d1h[r] = hi; d1l[r] = f2bf(lo); }
}

// both Whh layers -> WhhT fp16 [2,300,1200] each
__global__ void k_whhT2(const void* __restrict__ W1, const void* __restrict__ W2,
                        const int* __restrict__ flag,
                        u16* __restrict__ d1, u16* __restrict__ d2) {
    int i = blockIdx.x * 256 + threadIdx.x;
    if (i >= 2 * 720000) return;
    int f = *flag;
    int layer = i / 720000, r = i - layer * 720000;
    int dir = r / 360000, rr = r - dir * 360000;
    int k = rr / 1200, g = rr - k * 1200;
    const void* W = layer ? W2 : W1;
    u16 bits = f16(rdf(W, (size_t)dir * 360000 + (size_t)g * 300 + k, f));
    if (layer) d2[r] = bits; else d1[r] = bits;
}

// lin1_W [2,600,1200] -> A pads (k 0..600, mid part) and B pads (k 600..1200,
// v part), each [2,640,608] hi/lo
__global__ void k_pad_lin1AB(const void* __restrict__ W, const int* __restrict__ flag,
                             u16* __restrict__ Ahi, u16* __restrict__ Alo,
                             u16* __restrict__ Bhi, u16* __restrict__ Blo) {
    int i = blockIdx.x * 256 + threadIdx.x;
    if (i >= 2 * 640 * 608) return;
    int f = *flag;
    int it = i / (640 * 608), r = i - it * (640 * 608);
    int n = r / 608, k = r - n * 608;
    float va = 0.f, vb = 0.f;
    if (n < 600 && k < 600) {
        va = rdf(W, (size_t)it * 720000 + (size_t)n * 1200 + k, f);
        vb = rdf(W, (size_t)it * 720000 + (size_t)n * 1200 + 600 + k, f);
    }
    u16 h;
    h = f2bf(va); Ahi[i] = h; Alo[i] = f2bf(va - bf2f(h));
    h = f2bf(vb); Bhi[i] = h; Blo[i] = f2bf(vb - bf2f(h));
}

// e [512,600] fp32 -> ehi/elo [512,608] bf16
__global__ void k_esplit(const float* __restrict__ e,
                         u16* __restrict__ ehi, u16* __restrict__ elo) {
    int i = blockIdx.x * 256 + threadIdx.x;
    if (i >= 512 * 608) return;
    int r = i / 608, k = i - r * 608;
    float val = (k < 600) ? e[r * 600 + k] : 0.f;
    u16 h = f2bf(val);
    ehi[i] = h;
    elo[i] = f2bf(val - bf2f(h));
}

// smallf = pw(8192)|l2w(1200)|l2b(2)|fcw(1800)|fcb(3); bl[1280]; bias_t/a[2400]
__global__ void k_small(const void* pw, const void* l2w, const void* l2b,
                        const void* fcw, const void* fcb, const void* lb,
                        const void* b1i, const void* b1h, const void* b2i, const void* b2h,
                        const int* __restrict__ flag,
                        float* __restrict__ dst, float* __restrict__ bl,
                        float* __restrict__ bt, float* __restrict__ ba) {
    int i = blockIdx.x * 256 + threadIdx.x;
    int f = *flag;
    if (i < 8192)            dst[i] = rdf(pw, i, f);
    else if (i < 9392)       dst[i] = rdf(l2w, i - 8192, f);
    else if (i < 9394)       dst[i] = rdf(l2b, i - 9392, f);
    else if (i < 11194)      dst[i] = rdf(fcw, i - 9394, f);
    else if (i < 11197)      dst[i] = rdf(fcb, i - 11194, f);
    if (i < 1280) {
        int dir = i / 640, c = i - dir * 640;
        bl[i] = (c < 600) ? rdf(lb, dir * 600 + c, f) : 0.f;
    }
    if (i < 2400) {
        bt[i] = rdf(b1i, i, f) + rdf(b1h, i, f);
        ba[i] = rdf(b2i, i, f) + rdf(b2h, i, f);
    }
}

// ---------------- shared gather-GEMM tile (fp16 output) ----------------
__device__ __forceinline__ void gemm_emb_tile(
    const void* __restrict__ emb, const int* __restrict__ ids,
    int base, int rpb, int stride, int f,
    const u16* __restrict__ Bhi, const u16* __restrict__ Blo,
    const float* __restrict__ bias,
    u16* __restrict__ C, int ldc, int nstore, int bx, int by, int tid)
{
    int wave = tid >> 6, lane = tid & 63;
    int l15 = lane & 15, quad = lane >> 4;
    int m0 = bx * 64 + wave * 16;
    int n0 = by * 64;

    int m = m0 + l15;
    int b = m / rpb, j = m - b * rpb;
    int id = ids[b * stride + base + j];
    const float* arow_f = (const float*)emb + (size_t)id * 300;
    const u16*   arow_b = (const u16*)emb + (size_t)id * 300;

    const u16* Bp  = Bhi + (size_t)(n0 + l15) * 320 + quad * 8;
    const u16* Bp2 = Blo + (size_t)(n0 + l15) * 320 + quad * 8;

    floatx4 acc0 = {0.f, 0.f, 0.f, 0.f};
    floatx4 acc1 = acc0, acc2 = acc0, acc3 = acc0;

    for (int kc = 0; kc < 10; ++kc) {
        int ko = kc * 32 + quad * 8;
        short8 ahi, alo;
        if (f) {
            if (ko + 8 <= 300) {
                float4 fa = *(const float4*)(arow_f + ko);
                float4 fb = *(const float4*)(arow_f + ko + 4);
                float vv[8] = {fa.x, fa.y, fa.z, fa.w, fb.x, fb.y, fb.z, fb.w};
                #pragma unroll
                for (int t = 0; t < 8; ++t) {
                    u16 h = f2bf(vv[t]);
                    ahi[t] = (short)h;
                    alo[t] = (short)f2bf(vv[t] - bf2f(h));
                }
            } else {
                #pragma unroll
                for (int t = 0; t < 8; ++t) {
                    int k = ko + t;
                    float vv = (k < 300) ? arow_f[k] : 0.f;
                    u16 h = f2bf(vv);
                    ahi[t] = (short)h;
                    alo[t] = (short)f2bf(vv - bf2f(h));
                }
            }
        } else {
            #pragma unroll
            for (int t = 0; t < 8; ++t) {
                int k = ko + t;
                ahi[t] = (k < 300) ? (short)arow_b[k] : (short)0;
                alo[t] = 0;
            }
        }
        int ko2 = kc * 32;
        short8 bh0 = *(const short8*)(Bp + ko2);
        short8 bh1 = *(const short8*)(Bp + (size_t)16 * 320 + ko2);
        short8 bh2 = *(const short8*)(Bp + (size_t)32 * 320 + ko2);
        short8 bh3 = *(const short8*)(Bp + (size_t)48 * 320 + ko2);
        short8 bl0 = *(const short8*)(Bp2 + ko2);
        short8 bl1 = *(const short8*)(Bp2 + (size_t)16 * 320 + ko2);
        short8 bl2 = *(const short8*)(Bp2 + (size_t)32 * 320 + ko2);
        short8 bl3 = *(const short8*)(Bp2 + (size_t)48 * 320 + ko2);
        acc0 = MFMA(ahi, bh0, acc0, 0, 0, 0);
        acc1 = MFMA(ahi, bh1, acc1, 0, 0, 0);
        acc2 = MFMA(ahi, bh2, acc2, 0, 0, 0);
        acc3 = MFMA(ahi, bh3, acc3, 0, 0, 0);
        acc0 = MFMA(ahi, bl0, acc0, 0, 0, 0);
        acc1 = MFMA(ahi, bl1, acc1, 0, 0, 0);
        acc2 = MFMA(ahi, bl2, acc2, 0, 0, 0);
        acc3 = MFMA(ahi, bl3, acc3, 0, 0, 0);
        acc0 = MFMA(alo, bh0, acc0, 0, 0, 0);
        acc1 = MFMA(alo, bh1, acc1, 0, 0, 0);
        acc2 = MFMA(alo, bh2, acc2, 0, 0, 0);
        acc3 = MFMA(alo, bh3, acc3, 0, 0, 0);
    }

    #pragma unroll
    for (int c = 0; c < 4; ++c) {
        floatx4 acc = (c == 0) ? acc0 : (c == 1) ? acc1 : (c == 2) ? acc2 : acc3;
        int col = n0 + c * 16 + l15;
        if (col >= nstore) continue;
        float bb = bias[col];
        #pragma unroll
        for (int r = 0; r < 4; ++r) {
            int row = m0 + quad * 4 + r;
            C[(size_t)row * ldc + col] = f16(acc[r] + bb);
        }
    }
}

__global__ __launch_bounds__(256) void gemm_embk(
    const void* __restrict__ emb, const int* __restrict__ ids,
    int base, int rpb, int stride, const int* __restrict__ flag,
    const u16* __restrict__ Bhi, const u16* __restrict__ Blo,
    const float* __restrict__ bias,
    u16* __restrict__ C, int ldc, int nstore)
{
    gemm_emb_tile(emb, ids, base, rpb, stride, *flag, Bhi, Blo, bias,
                  C, ldc, nstore, blockIdx.x, blockIdx.y, threadIdx.x);
}

// ---------------- GEMM core: acc = (Ahi+Alo)[64,K] @ (Bhi+Blo)[64,K]^T ----------
__device__ __forceinline__ void gemm_core(
    const u16* __restrict__ Ap, const u16* __restrict__ Ap2,
    const u16* __restrict__ Bp, const u16* __restrict__ Bp2,
    int lda, int ldb, int nk,
    floatx4& acc0, floatx4& acc1, floatx4& acc2, floatx4& acc3)
{
    for (int kc = 0; kc < nk; ++kc) {
        int ko = kc * 32;
        short8 bh0 = *(const short8*)(Bp + ko);
        short8 bh1 = *(const short8*)(Bp + (size_t)16 * ldb + ko);
        short8 bh2 = *(const short8*)(Bp + (size_t)32 * ldb + ko);
        short8 bh3 = *(const short8*)(Bp + (size_t)48 * ldb + ko);
        short8 bl0 = *(const short8*)(Bp2 + ko);
        short8 bl1 = *(const short8*)(Bp2 + (size_t)16 * ldb + ko);
        short8 bl2 = *(const short8*)(Bp2 + (size_t)32 * ldb + ko);
        short8 bl3 = *(const short8*)(Bp2 + (size_t)48 * ldb + ko);
        short8 a  = *(const short8*)(Ap + ko);
        short8 al = *(const short8*)(Ap2 + ko);
        acc0 = MFMA(a, bh0, acc0, 0, 0, 0);
        acc1 = MFMA(a, bh1, acc1, 0, 0, 0);
        acc2 = MFMA(a, bh2, acc2, 0, 0, 0);
        acc3 = MFMA(a, bh3, acc3, 0, 0, 0);
        acc0 = MFMA(a, bl0, acc0, 0, 0, 0);
        acc1 = MFMA(a, bl1, acc1, 0, 0, 0);
        acc2 = MFMA(a, bl2, acc2, 0, 0, 0);
        acc3 = MFMA(a, bl3, acc3, 0, 0, 0);
        acc0 = MFMA(al, bh0, acc0, 0, 0, 0);
        acc1 = MFMA(al, bh1, acc1, 0, 0, 0);
        acc2 = MFMA(al, bh2, acc2, 0, 0, 0);
        acc3 = MFMA(al, bh3, acc3, 0, 0, 0);
    }
}

// EW = (ehi+elo)[512,608] @ l1wA[iter][640,608]^T -> fp32 [2][512][600]
__global__ __launch_bounds__(256) void gemm_ew(
    const u16* __restrict__ Ahi, const u16* __restrict__ Alo,
    const u16* __restrict__ l1a_hi, const u16* __restrict__ l1a_lo,
    float* __restrict__ EW)
{
    int tid = threadIdx.x;
    int wave = tid >> 6, lane = tid & 63;
    int l15 = lane & 15, quad = lane >> 4;
    int iter = blockIdx.z;
    int m0 = blockIdx.x * 64 + wave * 16;
    int n0 = blockIdx.y * 64;
    const u16* Ap  = Ahi + (size_t)(m0 + l15) * 608 + quad * 8;
    const u16* Ap2 = Alo + (size_t)(m0 + l15) * 608 + quad * 8;
    const u16* Bp  = l1a_hi + (size_t)iter * 640 * 608 + (size_t)(n0 + l15) * 608 + quad * 8;
    const u16* Bp2 = l1a_lo + (size_t)iter * 640 * 608 + (size_t)(n0 + l15) * 608 + quad * 8;
    floatx4 acc0 = {0.f, 0.f, 0.f, 0.f};
    floatx4 acc1 = acc0, acc2 = acc0, acc3 = acc0;
    gemm_core(Ap, Ap2, Bp, Bp2, 608, 608, 19, acc0, acc1, acc2, acc3);
    #pragma unroll
    for (int c = 0; c < 4; ++c) {
        floatx4 acc = (c == 0) ? acc0 : (c == 1) ? acc1 : (c == 2) ? acc2 : acc3;
        int col = n0 + c * 16 + l15;
        if (col >= 600) continue;
        #pragma unroll
        for (int r = 0; r < 4; ++r) {
            int row = m0 + quad * 4 + r;
            EW[((size_t)iter * 512 + row) * 600 + col] = acc[r];
        }
    }
}

// lin1: acc = vsplit @ l1wB^T ; epilogue adds alpha@EW + bias, gate, writes v
__global__ __launch_bounds__(256) void gemm_vt(
    const u16* __restrict__ vhi, const u16* __restrict__ vlo,
    const u16* __restrict__ Bhi, const u16* __restrict__ Blo,
    const float* __restrict__ bias,
    const float* __restrict__ EW, const float* __restrict__ a_sm,
    const float* __restrict__ tg, const float* __restrict__ pw,
    float* __restrict__ vio)
{
    __shared__ float al_s[64][8];
    __shared__ float ew_s[8][64];
    int tid = threadIdx.x;
    int wave = tid >> 6, lane = tid & 63;
    int l15 = lane & 15, quad = lane >> 4;
    int m0 = blockIdx.x * 64 + wave * 16;
    int n0 = blockIdx.y * 64;
    int row0 = blockIdx.x * 64;
    int bidx = row0 >> 7;                 // uniform per tile

    for (int i = tid; i < 512; i += 256)
        al_s[i >> 3][i & 7] = a_sm[(size_t)(row0 + (i >> 3)) * 8 + (i & 7)];
    for (int i = tid; i < 512; i += 256) {
        int a = i >> 6, cc = i & 63;
        int col = n0 + cc;
        ew_s[a][cc] = (col < 600) ? EW[((size_t)bidx * 8 + a) * 600 + col] : 0.f;
    }
    __syncthreads();

    const u16* Ap  = vhi + (size_t)(m0 + l15) * 608 + quad * 8;
    const u16* Ap2 = vlo + (size_t)(m0 + l15) * 608 + quad * 8;
    const u16* Bp  = Bhi + (size_t)(n0 + l15) * 608 + quad * 8;
    const u16* Bp2 = Blo + (size_t)(n0 + l15) * 608 + quad * 8;
    floatx4 acc0 = {0.f, 0.f, 0.f, 0.f};
    floatx4 acc1 = acc0, acc2 = acc0, acc3 = acc0;
    gemm_core(Ap, Ap2, Bp, Bp2, 608, 608, 19, acc0, acc1, acc2, acc3);

    #pragma unroll
    for (int c = 0; c < 4; ++c) {
        floatx4 acc = (c == 0) ? acc0 : (c == 1) ? acc1 : (c == 2) ? acc2 : acc3;
        int cc = c * 16 + l15;
        int col = n0 + cc;
        if (col >= 600) continue;
        float bb = bias[col];
        #pragma unroll
        for (int r = 0; r < 4; ++r) {
            int rr = wave * 16 + quad * 4 + r;
            int row = row0 + rr;
            float mid = 0.f;
            #pragma unroll
            for (int a = 0; a < 8; ++a) mid += al_s[rr][a] * ew_s[a][cc];
            float val = acc[r] + bb + mid;
            val = val > 0.f ? val : 0.01f * val;      // leaky_relu
            float t = tg[row];
            size_t vi = (size_t)row * 600 + col;
            float vv = vio[vi];
            vio[vi] = pw[row] * ((1.f - t) * val + t * vv);
        }
    }
}

// ---------------- fused LSTM + next-chunk xproj GEMM, with LDS W cache --------
// blocks [0,128): text chains. [128,nLstm): aspect chains (kk==0).
// [nLstm, ..): 64x64 gemm tiles for chunk kk+1 (256 active threads).
// LDS caches rows 0..7 of each k-group's 50 weight rows (115KB); rows 8..49
// streamed from L2 (16% fewer vmem instructions than r12).
__global__ __launch_bounds__(960, 1) void k_lstm6(
    const u16* __restrict__ xf, const u16* __restrict__ xb, int ldx, int rpb,
    int base_f, int base_b, const u16* __restrict__ whhT,
    const int* __restrict__ lens, float* __restrict__ out, int T, int init,
    float* __restrict__ hst, float* __restrict__ cst, int nsteps,
    const u16* __restrict__ xa, const u16* __restrict__ whhA,
    const int* __restrict__ lensA, float* __restrict__ outA,
    float* __restrict__ hstA, float* __restrict__ cstA, int nLstm,
    const void* __restrict__ emb, const int* __restrict__ text,
    int bf_next, int bb_next, const int* __restrict__ flag,
    const u16* __restrict__ wih_hi, const u16* __restrict__ wih_lo,
    const float* __restrict__ bias_t,
    u16* __restrict__ xf_next, u16* __restrict__ xb_next)
{
    __shared__ float h_s[300];
    __shared__ float part[6][1200];
    __shared__ u16 wlds[6][8][1200];
    int blk = blockIdx.x;
    if (blk >= nLstm) {                   // next-chunk gemm tile
        if (threadIdx.x >= 256) return;
        int g = blk - nLstm;
        int dirn = g / 608; int t = g - dirn * 608;
        int bx = t & 31, by = t >> 5;     // 32 x 19
        gemm_emb_tile(emb, text, dirn ? bb_next : bf_next, 32, 128, *flag,
                      wih_hi + (dirn ? 1200ull * 320 : 0),
                      wih_lo + (dirn ? 1200ull * 320 : 0),
                      bias_t + (dirn ? 1200 : 0),
                      dirn ? xb_next : xf_next, 1200, 1200, bx, by, threadIdx.x);
        return;
    }
    if (blk >= 128) {                     // fused aspect chain
        blk -= 128;
        xf = xa; xb = xa + 1200; ldx = 2400; rpb = 8;
        base_f = 0; base_b = 0;
        whhT = whhA; lens = lensA; out = outA; T = 8; init = 1;
        hst = hstA; cst = cstA; nsteps = 8;
    }
    int tid = threadIdx.x;
    int g6 = tid / 160, u = tid - g6 * 160;
    bool act = (u < 150);
    int b = blk >> 1, dir = blk & 1;
    int len = lens[b];
    float c = 0.f;
    const u16* wbase = whhT + (size_t)dir * 360000 + (size_t)g6 * 50 * 1200 + 8 * u;
    // preload LDS weight cache: rows 0..7 of this group's 50
    if (act) {
        #pragma unroll
        for (int r = 0; r < 8; ++r)
            *(uint4*)&wlds[g6][r][8 * u] = *(const uint4*)(wbase + (size_t)r * 1200);
    }
    if (tid < 300) {
        h_s[tid] = init ? 0.f : hst[(size_t)blk * 300 + tid];
        c = init ? 0.f : cst[(size_t)blk * 300 + tid];
    }
    __syncthreads();
    const u16* wstream = wbase + (size_t)8 * 1200;

    for (int s = 0; s < nsteps; ++s) {
        int pos = dir ? (base_b + nsteps - 1 - s) : (base_f + s);
        if (pos >= len) continue;           // block-uniform skip
        if (act) {
            float a0 = 0.f, a1 = 0.f, a2 = 0.f, a3 = 0.f;
            float a4 = 0.f, a5 = 0.f, a6 = 0.f, a7 = 0.f;
            const float* hs = h_s + g6 * 50;
            // LDS-cached rows 0..7
            #pragma unroll
            for (int i = 0; i < 8; ++i) {
                float hk = hs[i];
                uint4 wv = *(const uint4*)&wlds[g6][i][8 * u];
                float2 f0 = __half22float2(*(__half2*)&wv.x);
                float2 f1 = __half22float2(*(__half2*)&wv.y);
                float2 f2 = __half22float2(*(__half2*)&wv.z);
                float2 f3 = __half22float2(*(__half2*)&wv.w);
                a0 = fmaf(hk, f0.x, a0); a1 = fmaf(hk, f0.y, a1);
                a2 = fmaf(hk, f1.x, a2); a3 = fmaf(hk, f1.y, a3);
                a4 = fmaf(hk, f2.x, a4); a5 = fmaf(hk, f2.y, a5);
                a6 = fmaf(hk, f3.x, a6); a7 = fmaf(hk, f3.y, a7);
            }
            // streamed rows 8..49
            const u16* wp = wstream;
            #pragma unroll 7
            for (int i = 0; i < 42; ++i) {
                float hk = hs[8 + i];
                uint4 wv = *(const uint4*)wp;
                wp += 1200;
                float2 f0 = __half22float2(*(__half2*)&wv.x);
                float2 f1 = __half22float2(*(__half2*)&wv.y);
                float2 f2 = __half22float2(*(__half2*)&wv.z);
                float2 f3 = __half22float2(*(__half2*)&wv.w);
                a0 = fmaf(hk, f0.x, a0); a1 = fmaf(hk, f0.y, a1);
                a2 = fmaf(hk, f1.x, a2); a3 = fmaf(hk, f1.y, a3);
                a4 = fmaf(hk, f2.x, a4); a5 = fmaf(hk, f2.y, a5);
                a6 = fmaf(hk, f3.x, a6); a7 = fmaf(hk, f3.y, a7);
            }
            float* pp = &part[g6][8 * u];
            float4 w0 = {a0, a1, a2, a3};
            float4 w1 = {a4, a5, a6, a7};
            *(float4*)pp = w0;
            *(float4*)(pp + 4) = w1;
        }
        __syncthreads();
        if (tid < 300) {
            const u16* xr = dir ? (xb + (size_t)(b * rpb + pos - base_b) * ldx)
                                : (xf + (size_t)(b * rpb + pos - base_f) * ldx);
            float gi = h16(xr[tid]), gf = h16(xr[300 + tid]);
            float gg = h16(xr[600 + tid]), go = h16(xr[900 + tid]);
            #pragma unroll
            for (int g = 0; g < 6; ++g) {
                gi += part[g][tid];
                gf += part[g][300 + tid];
                gg += part[g][600 + tid];
                go += part[g][900 + tid];
            }
            gi = sigm(gi); gf = sigm(gf); gg = tanhf(gg); go = sigm(go);
            c = gf * c + gi * gg;
            float hn = go * tanhf(c);
            out[((size_t)b * T + pos) * 600 + dir * 300 + tid] = hn;
            h_s[tid] = hn;
        }
        __syncthreads();
    }
    if (tid < 300) {
        hst[(size_t)blk * 300 + tid] = h_s[tid];
        cst[(size_t)blk * 300 + tid] = c;
    }
}

// ---------------- scores+softmax+tgate+v-split (no cat, no mid) ----------------
__global__ __launch_bounds__(128) void k_scorev(
    const float* __restrict__ v, const float* __restrict__ e,
    const int* __restrict__ text, const int* __restrict__ asp,
    const float* __restrict__ l2w, const float* __restrict__ l2b, int iter,
    float* __restrict__ a_sm, float* __restrict__ tg,
    u16* __restrict__ vhi, u16* __restrict__ vlo)
{
    __shared__ float vs[600];
    __shared__ float red[2][9];
    int row = blockIdx.x;
    int b = row >> 7;
    int t = threadIdx.x, wv = t >> 6, lane = t & 63;
    const float* vrow = v + (size_t)row * 600;
    const float* eb = e + (size_t)b * 4800;
    const float* w2 = l2w + iter * 600;

    for (int d = t; d < 600; d += 128) vs[d] = vrow[d];
    __syncthreads();

    float acc[9];
    #pragma unroll
    for (int j = 0; j < 9; ++j) acc[j] = 0.f;
    for (int d = t; d < 600; d += 128) {
        float vv = vs[d];
        #pragma unroll
        for (int a = 0; a < 8; ++a) acc[a] += vv * eb[a * 600 + d];
        acc[8] += vv * w2[d];
    }
    #pragma unroll
    for (int off = 32; off >= 1; off >>= 1) {
        #pragma unroll
        for (int j = 0; j < 9; ++j) acc[j] += __shfl_down(acc[j], off, 64);
    }
    if (lane == 0) {
        #pragma unroll
        for (int j = 0; j < 9; ++j) red[wv][j] = acc[j];
    }
    __syncthreads();
    if (t == 0) {
        float dots[9];
        #pragma unroll
        for (int j = 0; j < 9; ++j) dots[j] = red[0][j] + red[1][j];
        tg[row] = sigm(dots[8] + l2b[iter]);
        bool sm = (text[row] != 0);
        float sc[8]; float mx = -INFINITY;
        #pragma unroll
        for (int a = 0; a < 8; ++a) {
            sc[a] = (sm && asp[b * 8 + a] != 0) ? dots[a] : NEGV;
            mx = fmaxf(mx, sc[a]);
        }
        float den = 0.f;
        #pragma unroll
        for (int a = 0; a < 8; ++a) { sc[a] = expf(sc[a] - mx); den += sc[a]; }
        float inv = 1.f / den;
        #pragma unroll
        for (int a = 0; a < 8; ++a) a_sm[(size_t)row * 8 + a] = sc[a] * inv;
    }
    for (int d = t; d < 608; d += 128) {
        float val = (d < 600) ? vs[d] : 0.f;
        u16 h = f2bf(val);
        vhi[(size_t)row * 608 + d] = h;
        vlo[(size_t)row * 608 + d] = f2bf(val - bf2f(h));
    }
}

// ---------------- final ----------------
__global__ void k_query(const float* __restrict__ e, const int* __restrict__ asp,
                        float* __restrict__ q) {
    int i = blockIdx.x * 256 + threadIdx.x;
    if (i >= 64 * 600) return;
    int b = i / 600, d = i - b * 600;
    float m = NEGV;
    for (int a = 0; a < 8; ++a)
        if (asp[b * 8 + a] != 0) m = fmaxf(m, e[(size_t)b * 4800 + a * 600 + d]);
    q[i] = m;
}

__global__ __launch_bounds__(128) void k_final(
    const float* __restrict__ v, const float* __restrict__ q,
    const int* __restrict__ text, const float* __restrict__ fcW,
    const float* __restrict__ fcb, const int* __restrict__ flag, void* __restrict__ outv)
{
    __shared__ float red[128];
    __shared__ float al[128];
    __shared__ float zz[600];
    int b = blockIdx.x, s = threadIdx.x;
    const float* vrow = v + (size_t)(b * 128 + s) * 600;
    const float* qb = q + (size_t)b * 600;
    float sc = 0.f;
    for (int d = 0; d < 600; ++d) sc += vrow[d] * qb[d];
    if (text[b * 128 + s] == 0) sc = NEGV;
    red[s] = sc; __syncthreads();
    for (int off = 64; off >= 1; off >>= 1) {
        if (s < off) red[s] = fmaxf(red[s], red[s + off]);
        __syncthreads();
    }
    float mx = red[0]; __syncthreads();
    float ex = expf(sc - mx);
    red[s] = ex; __syncthreads();
    for (int off = 64; off >= 1; off >>= 1) {
        if (s < off) red[s] += red[s + off];
        __syncthreads();
    }
    float alpha = ex / red[0];
    al[s] = alpha; __syncthreads();
    for (int d = s; d < 600; d += 128) {
        float z = 0.f;
        for (int s2 = 0; s2 < 128; ++s2) z += al[s2] * v[(size_t)(b * 128 + s2) * 600 + d];
        zz[d] = z;
    }
    __syncthreads();
    if (s < 3) {
        float o = 0.f;
        for (int d = 0; d < 600; ++d) o += zz[d] * fcW[s * 600 + d];
        o += fcb[s];
        if (*flag) ((float*)outv)[b * 3 + s] = o;
        else       ((u16*)outv)[b * 3 + s] = f2bf(o);
    }
}

// ---------------- host launch ----------------
extern "C" void kernel_launch(void* const* d_in, const int* in_sizes, int n_in,
                              void* d_out, int out_size, void* d_ws, size_t ws_size,
                              hipStream_t stream) {
    const int*  text   = (const int*)d_in[0];
    const int*  asp    = (const int*)d_in[1];
    const void* pw     = d_in[2];
    const void* emb    = d_in[3];
    const void* l1_Wih = d_in[4];
    const void* l1_Whh = d_in[5];
    const void* l1_bih = d_in[6];
    const void* l1_bhh = d_in[7];
    const void* l2_Wih = d_in[8];
    const void* l2_Whh = d_in[9];
    const void* l2_bih = d_in[10];
    const void* l2_bhh = d_in[11];
    const void* lin1_W = d_in[12];
    const void* lin1_b = d_in[13];
    const void* lin2_W = d_in[14];
    const void* lin2_b = d_in[15];
    const void* fcW    = d_in[16];
    const void* fcb    = d_in[17];
    (void)ws_size; (void)n_in; (void)in_sizes; (void)out_size;

    char* w = (char*)d_ws;
    size_t off = 0;
    auto alloc = [&](size_t bytes) -> void* {
        void* p = w + off;
        off += (bytes + 255) & ~(size_t)255;
        return p;
    };
    // ---- persistent (~22 MB) ----
    int*   flag     = (int*)  alloc(4);
    int*   lens     = (int*)  alloc(128ull * 4);
    float* bias_t   = (float*)alloc(2400ull * 4);
    float* bias_a   = (float*)alloc(2400ull * 4);
    float* bias_l1  = (float*)alloc(1280ull * 4);
    float* smallf   = (float*)alloc(11197ull * 4);
    float* tg       = (float*)alloc(8192ull * 4);
    float* a_sm     = (float*)alloc(8192ull * 8 * 4);
    float* query    = (float*)alloc(64ull * 600 * 4);
    float* hst_t    = (float*)alloc(128ull * 300 * 4);
    float* cst_t    = (float*)alloc(128ull * 300 * 4);
    float* hst_a    = (float*)alloc(128ull * 300 * 4);
    float* cst_a    = (float*)alloc(128ull * 300 * 4);
    float* e        = (float*)alloc(512ull * 600 * 4);
    float* v        = (float*)alloc(8192ull * 600 * 4);
    float* pw_f     = smallf;
    float* l2w_f    = smallf + 8192;
    float* l2b_f    = smallf + 9392;
    float* fcW_f    = smallf + 9394;
    float* fcb_f    = smallf + 11194;
    // ---- phase region (union ~31 MB) ----
    size_t phase_off = off;
    // phase A (LSTM)
    u16*   wiht_hi  = (u16*)  alloc(2432ull * 320 * 2);
    u16*   wiht_lo  = (u16*)  alloc(2432ull * 320 * 2);
    u16*   wiha_hi  = (u16*)  alloc(2432ull * 320 * 2);
    u16*   wiha_lo  = (u16*)  alloc(2432ull * 320 * 2);
    u16*   whhT_t   = (u16*)  alloc(720000ull * 2);   // fp16
    u16*   whhT_a   = (u16*)  alloc(720000ull * 2);   // fp16
    u16*   xf0      = (u16*)  alloc(2048ull * 1200 * 2);   // fp16 xproj dbuf
    u16*   xb0      = (u16*)  alloc(2048ull * 1200 * 2);
    u16*   xf1      = (u16*)  alloc(2048ull * 1200 * 2);
    u16*   xb1      = (u16*)  alloc(2048ull * 1200 * 2);
    u16*   xproj_a  = (u16*)  alloc(512ull * 2400 * 2);    // fp16
    // phase B (attention) aliases phase A (~30 MB)
    off = phase_off;
    u16*   l1a_hi   = (u16*)  alloc(2ull * 640 * 608 * 2);
    u16*   l1a_lo   = (u16*)  alloc(2ull * 640 * 608 * 2);
    u16*   l1b_hi   = (u16*)  alloc(2ull * 640 * 608 * 2);
    u16*   l1b_lo   = (u16*)  alloc(2ull * 640 * 608 * 2);
    u16*   ehi      = (u16*)  alloc(512ull * 608 * 2);
    u16*   elo      = (u16*)  alloc(512ull * 608 * 2);
    float* EW       = (float*)alloc(2ull * 512 * 600 * 4);
    u16*   vhi      = (u16*)  alloc(8192ull * 608 * 2);
    u16*   vlo      = (u16*)  alloc(8192ull * 608 * 2);

    hipMemsetAsync(v, 0, 8192ull * 600 * 4, stream);
    hipMemsetAsync(e, 0, 512ull * 600 * 4, stream);

    // ---- prep (merged) ----
    k_detect<<<1, 256, 0, stream>>>(emb, flag);
    k_prep_small<<<1, 128, 0, stream>>>(text, asp, lens);
    k_pad_wih2<<<(2 * 2432 * 320 + 255) / 256, 256, 0, stream>>>(
        l1_Wih, l2_Wih, flag, wiht_hi, wiht_lo, wiha_hi, wiha_lo);
    k_whhT2<<<(2 * 720000 + 255) / 256, 256, 0, stream>>>(
        l1_Whh, l2_Whh, flag, whhT_t, whhT_a);
    k_small<<<49, 256, 0, stream>>>(pw, lin2_W, lin2_b, fcW, fcb, lin1_b,
                                    l1_bih, l1_bhh, l2_bih, l2_bhh, flag,
                                    smallf, bias_l1, bias_t, bias_a);

    // ---- standalone xproj gemms: aspect + chunk 0 (fwd & bwd) ----
    gemm_embk<<<dim3(8, 38), 256, 0, stream>>>(emb, asp, 0, 8, 8, flag,
        wiha_hi, wiha_lo, bias_a, xproj_a, 2400, 2400);
    gemm_embk<<<dim3(32, 19), 256, 0, stream>>>(emb, text, 0, 32, 128, flag,
        wiht_hi, wiht_lo, bias_t, xf0, 1200, 1200);
    gemm_embk<<<dim3(32, 19), 256, 0, stream>>>(emb, text, 96, 32, 128, flag,
        wiht_hi + 1200ull * 320, wiht_lo + 1200ull * 320, bias_t + 1200,
        xb0, 1200, 1200);

    // ---- text path: 4 chunks of 32 positions; next chunk's xproj fused ----
    for (int kk = 0; kk < 4; ++kk) {
        int bf = 32 * kk;
        int bb = 96 - 32 * kk;
        u16* xfc = (kk & 1) ? xf1 : xf0;
        u16* xbc = (kk & 1) ? xb1 : xb0;
        u16* xfn = (kk & 1) ? xf0 : xf1;
        u16* xbn = (kk & 1) ? xb0 : xb1;
        int nLstm = (kk == 0) ? 256 : 128;
        int haveNext = (kk < 3);
        int nblk = nLstm + (haveNext ? 1216 : 0);
        k_lstm6<<<nblk, 960, 0, stream>>>(xfc, xbc, 1200, 32, bf, bb,
            whhT_t, lens, v, 128, kk == 0 ? 1 : 0, hst_t, cst_t, 32,
            xproj_a, whhT_a, lens + 64, e, hst_a, cst_a, nLstm,
            emb, text, bf + 32, bb - 32, flag, wiht_hi, wiht_lo, bias_t,
            xfn, xbn);
    }

    // ---- phase B prep (after last phase-A consumer) ----
    k_pad_lin1AB<<<(2 * 640 * 608 + 255) / 256, 256, 0, stream>>>(
        lin1_W, flag, l1a_hi, l1a_lo, l1b_hi, l1b_lo);
    k_esplit<<<(512 * 608 + 255) / 256, 256, 0, stream>>>(e, ehi, elo);
    gemm_ew<<<dim3(8, 10, 2), 256, 0, stream>>>(ehi, elo, l1a_hi, l1a_lo, EW);

    // ---- two attention iterations (un-chunked) ----
    for (int iter = 0; iter < 2; ++iter) {
        k_scorev<<<8192, 128, 0, stream>>>(v, e, text, asp, l2w_f, l2b_f,
            iter, a_sm, tg, vhi, vlo);
        gemm_vt<<<dim3(128, 10), 256, 0, stream>>>(vhi, vlo,
            l1b_hi + (size_t)iter * 640 * 608, l1b_lo + (size_t)iter * 640 * 608,
            bias_l1 + iter * 640, EW + (size_t)iter * 512 * 600,
            a_sm, tg, pw_f, v);
    }

    // ---- final ----
    k_query<<<150, 256, 0, stream>>>(e, asp, query);
    k_final<<<64, 128, 0, stream>>>(v, query, text, fcW_f, fcb_f, flag, d_out);
}